// Round 10
// baseline (1106.177 us; speedup 1.0000x reference)
//
#include <hip/hip_runtime.h>
#include <cstdint>
#include <cstddef>

#define B_   16
#define N_   2048
#define D_   128
#define F_   1024
#define H1_  512
#define OUT_ 50

static constexpr float BN_EPS = 1e-5f;

typedef __attribute__((ext_vector_type(8))) short short8;
typedef __attribute__((ext_vector_type(4))) float f32x4;

__device__ inline unsigned short f2bf(float f) {
  union { float f; unsigned u; } v; v.f = f;
  unsigned r = v.u + 0x7fff + ((v.u >> 16) & 1);
  return (unsigned short)(r >> 16);
}
__device__ inline float bf2f(unsigned short h) {
  union { unsigned u; float f; } v; v.u = ((unsigned)h) << 16; return v.f;
}

// async global->LDS, 16B per lane; LDS dest = wave-uniform base + lane*16
__device__ inline void dma16(const unsigned short* g, unsigned short* l) {
  __builtin_amdgcn_global_load_lds(
      (const __attribute__((address_space(1))) unsigned int*)g,
      (__attribute__((address_space(3))) unsigned int*)l, 16, 0, 0);
}

// ---------------------------------------------------------------------------
// Fold BN (+bias) into bf16 weights + fp32 bias.
// ---------------------------------------------------------------------------
__global__ void foldw_k(const float* __restrict__ W, int ldW,
                        const float* __restrict__ bias,
                        const float* __restrict__ g, const float* __restrict__ bb,
                        const float* __restrict__ m, const float* __restrict__ v,
                        unsigned short* __restrict__ Wb, float* __restrict__ biasF,
                        int O, int Opad, int K) {
  long i = (long)blockIdx.x * 256 + threadIdx.x;
  if (i >= (long)Opad * K) return;
  int o = (int)(i / K), k = (int)(i % K);
  float sc = 1.f, sh = 0.f;
  if (o < O && g) { sc = g[o] * rsqrtf(v[o] + BN_EPS); sh = bb[o] - m[o] * sc; }
  float w = (o < O) ? W[(long)o * ldW + k] * sc : 0.f;
  Wb[i] = f2bf(w);
  if (k == 0 && biasF) {
    float bf = 0.f;
    if (o < O) bf = (bias ? bias[o] : 0.f) * sc + sh;
    biasF[o] = bf;
  }
}

// ---------------------------------------------------------------------------
// conv1 (3->128) + bn + relu -> bf16 token-major. grid (N, g), block 128
// ---------------------------------------------------------------------------
__global__ void conv1_k(const float* __restrict__ x, const float* __restrict__ w1,
                        const float* __restrict__ g, const float* __restrict__ bb,
                        const float* __restrict__ m, const float* __restrict__ v,
                        unsigned short* __restrict__ h0b) {
  int o = threadIdx.x, n = blockIdx.x, b = blockIdx.y;
  const float* xb = x + (long)b * 3 * N_;
  float val = w1[o * 3 + 0] * xb[n] + w1[o * 3 + 1] * xb[N_ + n] + w1[o * 3 + 2] * xb[2 * N_ + n];
  float sc = g[o] * rsqrtf(v[o] + BN_EPS);
  val = val * sc + (bb[o] - m[o] * sc);
  h0b[((long)b * N_ + n) * D_ + o] = f2bf(fmaxf(val, 0.f));
}

// ---------------------------------------------------------------------------
// Token-output MFMA GEMM (swapped operands): out[n][o] bf16, O mult of 128.
// Tile TM x 128, BK=64, block 256 (2x2 waves). DMA staging + XOR swizzle.
// Epilogue: LDS repack -> 256B-row vector stores.
// flags: 16 add bf16 res after act | 32 pool partials
// ---------------------------------------------------------------------------
template <int TM>
__global__ __launch_bounds__(256, 4)
void gemm_tok(const unsigned short* __restrict__ Wb, int ldW,
              const unsigned short* __restrict__ A, long sA, int ldA,
              const float* __restrict__ biasF,
              const float* __restrict__ perBO, int ldPBO,
              const unsigned short* __restrict__ resH, long sRes, int ldRes,
              unsigned short* __restrict__ outH, long sOutH, int ldOutH,
              float* __restrict__ pmax, float* __restrict__ psum,
              int K, int act, int flags) {
  constexpr int MT = TM / 32;
  __shared__ unsigned short lAB[TM * 64 + 128 * 64];
  __shared__ float lpm[4][64], lps[4][64];
  unsigned short* lA = lAB;
  unsigned short* lB = lAB + TM * 64;
  unsigned short* lS = lAB;                 // repack tile TM x 128 (aliases)
  int tid = threadIdx.x;
  int n0 = blockIdx.x * TM, o0 = blockIdx.y * 128, b = blockIdx.z;
  int wave = tid >> 6, lane = tid & 63;
  int wr = wave >> 1, wc = wave & 1;
  int quad = lane >> 4, l15 = lane & 15;
  int rowL = lane >> 3;
  int kseg = (lane & 7) ^ rowL;
  const unsigned short* Ab = A + (long)b * sA + (long)n0 * ldA;
  const unsigned short* Wp = Wb + (long)o0 * ldW;

  f32x4 acc[MT][4];
  #pragma unroll
  for (int i = 0; i < MT; ++i)
    #pragma unroll
    for (int j = 0; j < 4; ++j) acc[i][j] = (f32x4){0.f, 0.f, 0.f, 0.f};

  for (int kc = 0; kc < K; kc += 64) {
    #pragma unroll
    for (int t = 0; t < 4; ++t) {
      int chunk = t * 4 + wave;
      dma16(Wp + (long)(chunk * 8 + rowL) * ldW + kc + kseg * 8, &lB[chunk * 512]);
      if (chunk < TM / 8)
        dma16(Ab + (long)(chunk * 8 + rowL) * ldA + kc + kseg * 8, &lA[chunk * 512]);
    }
    __syncthreads();
    #pragma unroll
    for (int kk = 0; kk < 2; ++kk) {
      short8 af[MT], bf[4];
      #pragma unroll
      for (int mt = 0; mt < MT; ++mt) {
        int r = wr * (TM / 2) + mt * 16 + l15;
        af[mt] = *(const short8*)&lA[r * 64 + (((kk * 4 + quad) ^ (l15 & 7)) * 8)];
      }
      #pragma unroll
      for (int ot = 0; ot < 4; ++ot) {
        int r = wc * 64 + ot * 16 + l15;
        bf[ot] = *(const short8*)&lB[r * 64 + (((kk * 4 + quad) ^ (l15 & 7)) * 8)];
      }
      #pragma unroll
      for (int mt = 0; mt < MT; ++mt)
        #pragma unroll
        for (int ot = 0; ot < 4; ++ot)
          acc[mt][ot] = __builtin_amdgcn_mfma_f32_16x16x32_bf16(bf[ot], af[mt], acc[mt][ot], 0, 0, 0);
    }
    __syncthreads();
  }

  bool doPool = (flags & 32) != 0;
  #pragma unroll
  for (int ot = 0; ot < 4; ++ot) {
    int obL = wc * 64 + ot * 16 + quad * 4;
    int ob = o0 + obL;
    float bi[4] = {0.f, 0.f, 0.f, 0.f};
    if (biasF) { float4 t = *(const float4*)&biasF[ob]; bi[0] = t.x; bi[1] = t.y; bi[2] = t.z; bi[3] = t.w; }
    if (perBO) {
      float4 t = *(const float4*)&perBO[(long)b * ldPBO + ob];
      bi[0] += t.x; bi[1] += t.y; bi[2] += t.z; bi[3] += t.w;
    }
    float pm4[4], ps4[4];
    #pragma unroll
    for (int r = 0; r < 4; ++r) { pm4[r] = -1e30f; ps4[r] = 0.f; }
    int g = obL >> 3, go = obL & 7;
    #pragma unroll
    for (int mt = 0; mt < MT; ++mt) {
      int nL = wr * (TM / 2) + mt * 16 + l15;
      float vals[4];
      #pragma unroll
      for (int r = 0; r < 4; ++r) {
        float val = acc[mt][ot][r] + bi[r];
        if (act == 1)      val = fmaxf(val, 0.f);
        else if (act == 2) val = (val >= 0.f) ? val : 0.2f * val;
        vals[r] = val;
      }
      if (flags & 16) {
        uint2 rv = *(const uint2*)&resH[(long)b * sRes + (long)(n0 + nL) * ldRes + ob];
        unsigned short rr[4];
        *(uint2*)rr = rv;
        #pragma unroll
        for (int r = 0; r < 4; ++r) vals[r] += bf2f(rr[r]);
      }
      unsigned short t4[4];
      #pragma unroll
      for (int r = 0; r < 4; ++r) {
        t4[r] = f2bf(vals[r]);
        if (doPool) { pm4[r] = fmaxf(pm4[r], vals[r]); ps4[r] += vals[r]; }
      }
      int gp = (g & 8) | ((g ^ (nL & 7)) & 7);
      *(uint2*)&lS[nL * 128 + gp * 8 + go] = *(uint2*)&t4[0];
    }
    if (doPool) {
      #pragma unroll
      for (int r = 0; r < 4; ++r) {
        float m = pm4[r], s = ps4[r];
        m = fmaxf(m, __shfl_xor(m, 1)); s += __shfl_xor(s, 1);
        m = fmaxf(m, __shfl_xor(m, 2)); s += __shfl_xor(s, 2);
        m = fmaxf(m, __shfl_xor(m, 4)); s += __shfl_xor(s, 4);
        m = fmaxf(m, __shfl_xor(m, 8)); s += __shfl_xor(s, 8);
        if (l15 == 0) { lpm[wave][ot * 16 + quad * 4 + r] = m; lps[wave][ot * 16 + quad * 4 + r] = s; }
      }
    }
  }
  __syncthreads();
  {
    int r0 = tid >> 4, s = tid & 15;
    #pragma unroll
    for (int it = 0; it < TM / 16; ++it) {
      int row = it * 16 + r0;
      int sp = (s & 8) | ((s ^ (row & 7)) & 7);
      short8 v = *(const short8*)&lS[row * 128 + sp * 8];
      *(short8*)&outH[(long)b * sOutH + (long)(n0 + row) * ldOutH + o0 + s * 8] = v;
    }
  }
  if (doPool && tid < 128) {
    int wcx = tid >> 6, ol = tid & 63;
    float m = fmaxf(lpm[wcx][ol], lpm[wcx + 2][ol]);
    float s = lps[wcx][ol] + lps[wcx + 2][ol];
    int o = o0 + wcx * 64 + ol;
    pmax[((long)b * 16 + blockIdx.x) * 1024 + o] = m;
    psum[((long)b * 16 + blockIdx.x) * 1024 + o] = s;
  }
}

// ---------------------------------------------------------------------------
// Channel-output MFMA GEMM (unswapped): out[o][n] fp32 or bf16; O guarded.
// ---------------------------------------------------------------------------
template <int TM>
__global__ __launch_bounds__(256, 4)
void gemm_chan(const unsigned short* __restrict__ Wb, int ldW,
               const unsigned short* __restrict__ A, long sA, int ldA,
               const float* __restrict__ biasF,
               float* __restrict__ outF, long sOutF, int ldOutF,
               unsigned short* __restrict__ outH, long sOutH, int ldOutH,
               int K, int O, int act) {
  constexpr int MT = TM / 32;
  __shared__ unsigned short lA[TM * 64];
  __shared__ unsigned short lB[128 * 64];
  int tid = threadIdx.x;
  int n0 = blockIdx.x * TM, o0 = blockIdx.y * 128, b = blockIdx.z;
  int wave = tid >> 6, lane = tid & 63;
  int wr = wave >> 1, wc = wave & 1;
  int quad = lane >> 4, l15 = lane & 15;
  int rowL = lane >> 3;
  int kseg = (lane & 7) ^ rowL;
  const unsigned short* Ab = A + (long)b * sA + (long)n0 * ldA;
  const unsigned short* Wp = Wb + (long)o0 * ldW;

  f32x4 acc[MT][4];
  #pragma unroll
  for (int i = 0; i < MT; ++i)
    #pragma unroll
    for (int j = 0; j < 4; ++j) acc[i][j] = (f32x4){0.f, 0.f, 0.f, 0.f};

  for (int kc = 0; kc < K; kc += 64) {
    #pragma unroll
    for (int t = 0; t < 4; ++t) {
      int chunk = t * 4 + wave;
      dma16(Wp + (long)(chunk * 8 + rowL) * ldW + kc + kseg * 8, &lB[chunk * 512]);
      if (chunk < TM / 8)
        dma16(Ab + (long)(chunk * 8 + rowL) * ldA + kc + kseg * 8, &lA[chunk * 512]);
    }
    __syncthreads();
    #pragma unroll
    for (int kk = 0; kk < 2; ++kk) {
      short8 af[MT], bf[4];
      #pragma unroll
      for (int mt = 0; mt < MT; ++mt) {
        int r = wr * (TM / 2) + mt * 16 + l15;
        af[mt] = *(const short8*)&lA[r * 64 + (((kk * 4 + quad) ^ (l15 & 7)) * 8)];
      }
      #pragma unroll
      for (int ot = 0; ot < 4; ++ot) {
        int r = wc * 64 + ot * 16 + l15;
        bf[ot] = *(const short8*)&lB[r * 64 + (((kk * 4 + quad) ^ (l15 & 7)) * 8)];
      }
      #pragma unroll
      for (int mt = 0; mt < MT; ++mt)
        #pragma unroll
        for (int ot = 0; ot < 4; ++ot)
          acc[mt][ot] = __builtin_amdgcn_mfma_f32_16x16x32_bf16(af[mt], bf[ot], acc[mt][ot], 0, 0, 0);
    }
    __syncthreads();
  }

  #pragma unroll
  for (int ot = 0; ot < 4; ++ot) {
    int o = o0 + wc * 64 + ot * 16 + l15;
    if (o >= O) continue;
    float bi = biasF ? biasF[o] : 0.f;
    #pragma unroll
    for (int mt = 0; mt < MT; ++mt) {
      int nb = n0 + wr * (TM / 2) + mt * 16 + quad * 4;
      float vals[4];
      #pragma unroll
      for (int r = 0; r < 4; ++r) {
        float val = acc[mt][ot][r] + bi;
        if (act == 1)      val = fmaxf(val, 0.f);
        else if (act == 2) val = (val >= 0.f) ? val : 0.2f * val;
        vals[r] = val;
      }
      if (outF)
        *(float4*)&outF[(long)b * sOutF + (long)o * ldOutF + nb] = *(float4*)vals;
      if (outH) {
        unsigned short t[4];
        #pragma unroll
        for (int r = 0; r < 4; ++r) t[r] = f2bf(vals[r]);
        *(uint2*)&outH[(long)b * sOutH + (long)o * ldOutH + nb] = *(uint2*)&t[0];
      }
    }
  }
}

// ---------------------------------------------------------------------------
// Gram stats + E materialization.
// lw[n] = mx[n] + log(rs[n]);  E_T[m][n] = E[n][m] (= E[m][n], symmetric),
// stored bf16 row-major [2048][2048] per batch via b64 stores.
// grid (g, 32): b fastest -> XCD = b%8. Double-buffered LDS, 1 barrier/chunk.
// ---------------------------------------------------------------------------
__global__ __launch_bounds__(256)
void gram_lw(const unsigned short* __restrict__ xk, long sXk,
             float* __restrict__ lw, unsigned short* __restrict__ eT) {
  __shared__ unsigned short lK[2][64 * 128];
  int tid = threadIdx.x, wave = tid >> 6, lane = tid & 63;
  int quad = lane >> 4, l15 = lane & 15;
  int rowL4 = lane >> 4, s16 = lane & 15;
  int n0 = blockIdx.y * 64, b = blockIdx.x;
  const unsigned short* Kp = xk + (long)b * sXk;
  unsigned short* eTp = eT + (long)b * 4194304;
  short8 afr[4];
  {
    const unsigned short* arow = Kp + (long)(n0 + wave * 16 + l15) * 128;
    #pragma unroll
    for (int kf = 0; kf < 4; ++kf) afr[kf] = *(const short8*)(arow + kf * 32 + quad * 8);
  }
  float runm[4], runs[4];
  #pragma unroll
  for (int r = 0; r < 4; ++r) { runm[r] = -1e30f; runs[r] = 0.f; }

  auto stage = [&](int ch, int bf) {
    #pragma unroll
    for (int t = 0; t < 4; ++t) {
      int c = t * 4 + wave;
      int row = c * 4 + rowL4;
      int gseg = (s16 & 8) | ((s16 ^ (row & 7)) & 7);
      dma16(Kp + (long)(ch * 64 + row) * 128 + gseg * 8, &lK[bf][c * 512]);
    }
  };
  stage(0, 0);

  for (int ch = 0; ch < 32; ++ch) {
    __syncthreads();
    int bf = ch & 1;
    if (ch + 1 < 32) stage(ch + 1, bf ^ 1);
    f32x4 sv[4];
    #pragma unroll
    for (int mf = 0; mf < 4; ++mf) {
      f32x4 s = (f32x4){0.f, 0.f, 0.f, 0.f};
      #pragma unroll
      for (int kf = 0; kf < 4; ++kf) {
        int r = mf * 16 + l15, q = kf * 4 + quad;
        int sp = (q & 8) | ((q ^ (r & 7)) & 7);
        short8 bfr = *(const short8*)&lK[bf][r * 128 + sp * 8];
        s = __builtin_amdgcn_mfma_f32_16x16x32_bf16(afr[kf], bfr, s, 0, 0, 0);
      }
      sv[mf] = s;
    }
    // store E_T[m][n]: m = ch*64+mf*16+l15 (row), n = n0+wave*16+quad*4+r
    #pragma unroll
    for (int mf = 0; mf < 4; ++mf) {
      unsigned short t4[4];
      #pragma unroll
      for (int r = 0; r < 4; ++r) t4[r] = f2bf(sv[mf][r]);
      long mrow = (long)(ch * 64 + mf * 16 + l15);
      *(uint2*)&eTp[mrow * 2048 + n0 + wave * 16 + quad * 4] = *(uint2*)&t4[0];
    }
    #pragma unroll
    for (int r = 0; r < 4; ++r) {
      float e0 = sv[0][r], e1 = sv[1][r], e2 = sv[2][r], e3 = sv[3][r];
      float cm = fmaxf(fmaxf(e0, e1), fmaxf(e2, e3));
      float mn = fmaxf(runm[r], cm);
      runs[r] = runs[r] * __expf(runm[r] - mn) +
                (__expf(e0 - mn) + __expf(e1 - mn)) + (__expf(e2 - mn) + __expf(e3 - mn));
      runm[r] = mn;
    }
  }
  #pragma unroll
  for (int r = 0; r < 4; ++r) {
    float m = runm[r], s = runs[r];
    #pragma unroll
    for (int off = 1; off < 16; off <<= 1) {
      float mo = __shfl_xor(m, off), so = __shfl_xor(s, off);
      float mn = fmaxf(m, mo);
      s = s * __expf(m - mn) + so * __expf(mo - mn);
      m = mn;
    }
    if (l15 == 0) {
      int n = n0 + wave * 16 + quad * 4 + r;
      lw[(long)b * 2048 + n] = m + __logf(s);
    }
  }
}

// ---------------------------------------------------------------------------
// PV from cached E: p[m][n] = exp(E_T[m][n] - lw[n]);  cs[m] = sum_n p;
// xrb[m][d] = bf16( li[m][d] - (sum_n p[m][n]*xv[d][n]) / (1e-9+cs[m]) )
// No QK recompute, no lP round-trip: E tile staged via DMA, exp into A-frags.
// grid (g, 32): b fastest. Double-buffered E/V, one barrier per chunk.
// ---------------------------------------------------------------------------
__global__ __launch_bounds__(256)
void pv_k(const unsigned short* __restrict__ eT,
          const unsigned short* __restrict__ xv, long sXv,
          const float* __restrict__ lw,
          const unsigned short* __restrict__ lib, long sLi, int ldLi,
          unsigned short* __restrict__ xrb, long sXr) {
  __shared__ unsigned short lE[2][64 * 64];
  __shared__ unsigned short lV[2][128 * 64];
  __shared__ float lwt[2][64];
  int tid = threadIdx.x, wave = tid >> 6, lane = tid & 63;
  int quad = lane >> 4, l15 = lane & 15;
  int rowL8 = lane >> 3, s8 = lane & 7;
  int m0 = blockIdx.y * 64, b = blockIdx.x;
  const unsigned short* Ep = eT + (long)b * 4194304 + (long)m0 * 2048;
  const unsigned short* Vp = xv + (long)b * sXv;
  f32x4 acc[8];
  #pragma unroll
  for (int dt = 0; dt < 8; ++dt) acc[dt] = (f32x4){0.f, 0.f, 0.f, 0.f};
  float runc = 0.f;

  auto stage = [&](int ch, int bf) {
    #pragma unroll
    for (int t = 0; t < 2; ++t) {
      int c = t * 4 + wave;
      int rowE = c * 8 + rowL8;
      int gseg = s8 ^ (rowE & 7);
      dma16(Ep + (long)rowE * 2048 + ch * 64 + gseg * 8, &lE[bf][c * 512]);
    }
    #pragma unroll
    for (int t = 0; t < 4; ++t) {
      int c = t * 4 + wave;
      int rowV = c * 8 + rowL8;
      int gsegV = s8 ^ (rowV & 7);
      dma16(Vp + (long)rowV * 2048 + ch * 64 + gsegV * 8, &lV[bf][c * 512]);
    }
    if (tid < 64) lwt[bf][tid] = lw[(long)b * 2048 + ch * 64 + tid];
  };
  stage(0, 0);

  int rowm = wave * 16 + l15;
  for (int ch = 0; ch < 32; ++ch) {
    __syncthreads();
    int bf = ch & 1;
    if (ch + 1 < 32) stage(ch + 1, bf ^ 1);
    #pragma unroll
    for (int kc = 0; kc < 2; ++kc) {
      int sp = (kc * 4 + quad) ^ (l15 & 7);
      short8 e8 = *(const short8*)&lE[bf][rowm * 64 + sp * 8];
      const float* lp = &lwt[bf][kc * 32 + quad * 8];
      float4 w0 = *(const float4*)lp;
      float4 w1 = *(const float4*)(lp + 4);
      float lwv[8] = {w0.x, w0.y, w0.z, w0.w, w1.x, w1.y, w1.z, w1.w};
      unsigned short pb[8];
      #pragma unroll
      for (int j = 0; j < 8; ++j) {
        float p = __expf(bf2f((unsigned short)e8[j]) - lwv[j]);
        runc += p;
        pb[j] = f2bf(p);
      }
      short8 pa = *(short8*)&pb[0];
      #pragma unroll
      for (int dt = 0; dt < 8; ++dt) {
        int r = dt * 16 + l15;
        int spv = (kc * 4 + quad) ^ (r & 7);
        short8 vb = *(const short8*)&lV[bf][r * 64 + spv * 8];
        acc[dt] = __builtin_amdgcn_mfma_f32_16x16x32_bf16(pa, vb, acc[dt], 0, 0, 0);
      }
    }
  }
  float s = runc;
  s += __shfl_xor(s, 16);
  s += __shfl_xor(s, 32);
  float inv = 1.f / (1e-9f + s);
  float inv4[4];
  #pragma unroll
  for (int r = 0; r < 4; ++r) inv4[r] = __shfl(inv, quad * 4 + r);
  #pragma unroll
  for (int dt = 0; dt < 8; ++dt) {
    int d = dt * 16 + l15;
    #pragma unroll
    for (int r = 0; r < 4; ++r) {
      int m = m0 + wave * 16 + quad * 4 + r;
      float lv = bf2f(lib[(long)b * sLi + (long)m * ldLi + d]);
      xrb[(long)b * sXr + (long)m * 128 + d] = f2bf(lv - acc[dt][r] * inv4[r]);
    }
  }
}

// ---------------------------------------------------------------------------
__global__ void poolred_k(const float* __restrict__ pmax, const float* __restrict__ psum,
                          float* __restrict__ xmax, float* __restrict__ xavg) {
  int f = blockIdx.x * 256 + threadIdx.x, b = blockIdx.y;
  float mx = -1e30f, s = 0.f;
  #pragma unroll
  for (int t = 0; t < 16; ++t) {
    mx = fmaxf(mx, pmax[((long)b * 16 + t) * 1024 + f]);
    s += psum[((long)b * 16 + t) * 1024 + f];
  }
  xmax[(long)b * 1024 + f] = mx;
  xavg[(long)b * 1024 + f] = s * (1.f / 2048.f);
}

// pt[b][o] = sc1[o] * ( ws1[o][1024:2048].xmax + ws1[o][2048:3072].xavg )
__global__ __launch_bounds__(256)
void poolterm_k(const float* __restrict__ ws1, const float* __restrict__ xmax,
                const float* __restrict__ xavg,
                const float* __restrict__ bg, const float* __restrict__ bv,
                float* __restrict__ pt) {
  int o = blockIdx.x, b = blockIdx.y, tid = threadIdx.x;
  const float* w = ws1 + (long)o * 3072;
  float s = 0.f;
  #pragma unroll
  for (int it = 0; it < 4; ++it) {
    int c = tid + it * 256;
    s += w[1024 + c] * xmax[(long)b * 1024 + c] + w[2048 + c] * xavg[(long)b * 1024 + c];
  }
  #pragma unroll
  for (int off = 32; off; off >>= 1) s += __shfl_xor(s, off);
  __shared__ float rsm[4];
  if ((tid & 63) == 0) rsm[tid >> 6] = s;
  __syncthreads();
  if (tid == 0) {
    float sc = bg[o] * rsqrtf(bv[o] + BN_EPS);
    pt[(long)b * H1_ + o] = sc * (rsm[0] + rsm[1] + rsm[2] + rsm[3]);
  }
}

// ---------------------------------------------------------------------------
extern "C" void kernel_launch(void* const* d_in, const int* in_sizes, int n_in,
                              void* d_out, int out_size, void* d_ws, size_t ws_size,
                              hipStream_t stream) {
  const float* x      = (const float*)d_in[0];
  const float* w1     = (const float*)d_in[1];
  const float* w2     = (const float*)d_in[2];
  const float* bn1_g  = (const float*)d_in[3];
  const float* bn1_b  = (const float*)d_in[4];
  const float* bn1_m  = (const float*)d_in[5];
  const float* bn1_v  = (const float*)d_in[6];
  const float* bn2_g  = (const float*)d_in[7];
  const float* bn2_b  = (const float*)d_in[8];
  const float* bn2_m  = (const float*)d_in[9];
  const float* bn2_v  = (const float*)d_in[10];
  const float* sa_wqk = (const float*)d_in[11];
  const float* sa_wv  = (const float*)d_in[12];
  const float* sa_bv  = (const float*)d_in[13];
  const float* sa_wt  = (const float*)d_in[14];
  const float* sa_bt  = (const float*)d_in[15];
  const float* sa_g   = (const float*)d_in[16];
  const float* sa_b   = (const float*)d_in[17];
  const float* sa_m   = (const float*)d_in[18];
  const float* sa_v   = (const float*)d_in[19];
  const float* wf     = (const float*)d_in[20];
  const float* bnf_g  = (const float*)d_in[21];
  const float* bnf_b  = (const float*)d_in[22];
  const float* bnf_m  = (const float*)d_in[23];
  const float* bnf_v  = (const float*)d_in[24];
  const float* ws1    = (const float*)d_in[25];
  const float* bs1    = (const float*)d_in[26];
  const float* bns1_g = (const float*)d_in[27];
  const float* bns1_b = (const float*)d_in[28];
  const float* bns1_m = (const float*)d_in[29];
  const float* bns1_v = (const float*)d_in[30];
  const float* ws2    = (const float*)d_in[31];
  const float* bs2    = (const float*)d_in[32];
  const float* bns2_g = (const float*)d_in[33];
  const float* bns2_b = (const float*)d_in[34];
  const float* bns2_m = (const float*)d_in[35];
  const float* bns2_v = (const float*)d_in[36];
  float* out = (float*)d_out;

  float* ws = (float*)d_ws;
  size_t off = 0;
  auto alloc  = [&](size_t n) { float* p = ws + off; off += (n + 63) & ~(size_t)63; return p; };
  auto allocH = [&](size_t n) { return (unsigned short*)alloc((n + 1) / 2); };

  unsigned short* w2b  = allocH(128 * 128);
  unsigned short* wqkb = allocH(4 * 128 * 128);
  unsigned short* wvb  = allocH(4 * 128 * 128);
  unsigned short* wtb  = allocH(4 * 128 * 128);
  unsigned short* wfb  = allocH((size_t)F_ * 512);
  unsigned short* ws1b = allocH((size_t)H1_ * 1024);
  unsigned short* ws2b = allocH((size_t)128 * 512);
  float* bias_w2 = alloc(128);
  float* bias_v  = alloc(512);
  float* bias_t  = alloc(512);
  float* bias_f  = alloc(1024);
  float* bias_s1 = alloc(512);
  float* bias_s2 = alloc(128);
  float* lwB  = alloc((size_t)16 * 2048);
  float* pmax = alloc((size_t)16 * 16 * 1024);
  float* psum = alloc((size_t)16 * 16 * 1024);
  float* xmaxB = alloc((size_t)16 * 1024);
  float* xavgB = alloc((size_t)16 * 1024);
  float* ptB   = alloc((size_t)16 * 512);
  size_t fixedOff = off;

  // per-batch (floats): h1b 131072 + featsb 524288 + fusedb 1048576 +
  //   xkb 131072 + xvb 131072 + xrb 131072 + E_T 2097152
  const size_t perB = 131072 + 524288 + 1048576 + 131072 + 131072 + 131072 + 2097152;
  size_t wsFloats = ws_size / 4;
  int Gb = 1;
  for (int c : {16, 8, 4, 2, 1}) {
    if (fixedOff + (size_t)c * perB + 4096 <= wsFloats) { Gb = c; break; }
  }

  unsigned short* h1b    = allocH((size_t)Gb * 262144);
  unsigned short* featsb = allocH((size_t)Gb * 1048576);   // hs1b aliases
  unsigned short* fusedb = allocH((size_t)Gb * 2097152);
  unsigned short* xkb    = allocH((size_t)Gb * 262144);
  unsigned short* xvb    = allocH((size_t)Gb * 262144);
  unsigned short* xrb    = allocH((size_t)Gb * 262144);    // h0b aliases
  unsigned short* eTb    = allocH((size_t)Gb * 4194304);
  unsigned short* h0b  = xrb;
  unsigned short* hs1b = featsb;

  foldw_k<<<64, 256, 0, stream>>>(w2, 128, nullptr, bn2_g, bn2_b, bn2_m, bn2_v,
                                  w2b, bias_w2, 128, 128, 128);
  for (int i = 0; i < 4; ++i) {
    foldw_k<<<64, 256, 0, stream>>>(sa_wqk + (size_t)i * 16384, 128, nullptr,
                                    nullptr, nullptr, nullptr, nullptr,
                                    wqkb + (size_t)i * 16384, nullptr, 128, 128, 128);
    foldw_k<<<64, 256, 0, stream>>>(sa_wv + (size_t)i * 16384, 128, sa_bv + i * 128,
                                    nullptr, nullptr, nullptr, nullptr,
                                    wvb + (size_t)i * 16384, bias_v + i * 128, 128, 128, 128);
    foldw_k<<<64, 256, 0, stream>>>(sa_wt + (size_t)i * 16384, 128, sa_bt + i * 128,
                                    sa_g + i * 128, sa_b + i * 128, sa_m + i * 128, sa_v + i * 128,
                                    wtb + (size_t)i * 16384, bias_t + i * 128, 128, 128, 128);
  }
  foldw_k<<<2048, 256, 0, stream>>>(wf, 512, nullptr, bnf_g, bnf_b, bnf_m, bnf_v,
                                    wfb, bias_f, 1024, 1024, 512);
  foldw_k<<<2048, 256, 0, stream>>>(ws1, 3072, bs1, bns1_g, bns1_b, bns1_m, bns1_v,
                                    ws1b, bias_s1, 512, 512, 1024);
  foldw_k<<<256, 256, 0, stream>>>(ws2, 512, bs2, bns2_g, bns2_b, bns2_m, bns2_v,
                                   ws2b, bias_s2, 50, 128, 512);

  const long sAct = 262144, sFeat = 1048576, sFus = 2097152;
  for (int b0 = 0; b0 < B_; b0 += Gb) {
    int g = Gb;
    conv1_k<<<dim3(N_, g), 128, 0, stream>>>(x + (long)b0 * 3 * N_, w1,
                                             bn1_g, bn1_b, bn1_m, bn1_v, h0b);
    // conv2+bn2+relu -> h1b bf16
    gemm_tok<64><<<dim3(32, 1, g), 256, 0, stream>>>(
        w2b, 128, h0b, sAct, 128, bias_w2, nullptr, 0, nullptr, 0, 0,
        h1b, sAct, 128, nullptr, nullptr, 128, 1, 0);

    for (int i = 0; i < 4; ++i) {
      const unsigned short* lib = (i == 0) ? h1b : featsb + (size_t)(i - 1) * 128;
      int ldLi = (i == 0) ? 128 : 512;
      long sLi = (i == 0) ? sAct : sFeat;
      // xk (bf16 token)
      gemm_tok<64><<<dim3(32, 1, g), 256, 0, stream>>>(
          wqkb + (size_t)i * 16384, 128, lib, sLi, ldLi, nullptr, nullptr, 0,
          nullptr, 0, 0, xkb, sAct, 128, nullptr, nullptr, 128, 0, 0);
      // xv (bf16 channel, +bv)
      gemm_chan<64><<<dim3(32, 1, g), 256, 0, stream>>>(
          wvb + (size_t)i * 16384, 128, lib, sLi, ldLi, bias_v + i * 128,
          nullptr, 0, 0, xvb, sAct, 2048, 128, 128, 0);
      gram_lw<<<dim3(g, 32), 256, 0, stream>>>(xkb, sAct, lwB, eTb);
      pv_k<<<dim3(g, 32), 256, 0, stream>>>(eTb, xvb, sAct, lwB,
                                            lib, sLi, ldLi, xrb, sAct);
      // feats_i = li + relu(wt' @ (li - xr) + bt')   (res = bf16 li)
      gemm_tok<64><<<dim3(32, 1, g), 256, 0, stream>>>(
          wtb + (size_t)i * 16384, 128, xrb, sAct, 128, bias_t + i * 128, nullptr, 0,
          lib, sLi, ldLi,
          featsb + (size_t)i * 128, sFeat, 512, nullptr, nullptr, 128, 1, 16);
    }

    // fused = leaky(wf' @ feats + bf') -> bf16 + pool partials
    gemm_tok<128><<<dim3(16, 8, g), 256, 0, stream>>>(
        wfb, 512, featsb, sFeat, 512, bias_f, nullptr, 0, nullptr, 0, 0,
        fusedb, sFus, 1024, pmax, psum, 512, 2, 32);
    poolred_k<<<dim3(4, g), 256, 0, stream>>>(pmax, psum, xmaxB, xavgB);
    poolterm_k<<<dim3(512, g), 256, 0, stream>>>(ws1, xmaxB, xavgB, bns1_g, bns1_v, ptB);
    // hs1 = relu(ws1' @ fused + bs1' + pt) -> bf16
    gemm_tok<128><<<dim3(16, 4, g), 256, 0, stream>>>(
        ws1b, 1024, fusedb, sFus, 1024, bias_s1, ptB, 512, nullptr, 0, 0,
        hs1b, sFeat, 512, nullptr, nullptr, 1024, 1, 0);
    // out = relu(ws2' @ hs1 + bs2') -> fp32 channel-major
    gemm_chan<64><<<dim3(32, 1, g), 256, 0, stream>>>(
        ws2b, 512, hs1b, sFeat, 512, bias_s2,
        out + (long)b0 * OUT_ * N_, (long)OUT_ * N_, 2048, nullptr, 0, 0,
        512, 50, 1);
  }
}

// Round 11
// 787.928 us; speedup vs baseline: 1.4039x; 1.4039x over previous
//
#include <hip/hip_runtime.h>
#include <cstdint>
#include <cstddef>

#define B_   16
#define N_   2048
#define D_   128
#define F_   1024
#define H1_  512
#define OUT_ 50

static constexpr float BN_EPS = 1e-5f;

typedef __attribute__((ext_vector_type(8))) short short8;
typedef __attribute__((ext_vector_type(4))) float f32x4;

__device__ inline unsigned short f2bf(float f) {
  union { float f; unsigned u; } v; v.f = f;
  unsigned r = v.u + 0x7fff + ((v.u >> 16) & 1);
  return (unsigned short)(r >> 16);
}
__device__ inline float bf2f(unsigned short h) {
  union { unsigned u; float f; } v; v.u = ((unsigned)h) << 16; return v.f;
}

// async global->LDS, 16B per lane; LDS dest = wave-uniform base + lane*16
__device__ inline void dma16(const unsigned short* g, unsigned short* l) {
  __builtin_amdgcn_global_load_lds(
      (const __attribute__((address_space(1))) unsigned int*)g,
      (__attribute__((address_space(3))) unsigned int*)l, 16, 0, 0);
}

// ---------------------------------------------------------------------------
// Fold BN (+bias) into bf16 weights + fp32 bias.
// ---------------------------------------------------------------------------
__global__ void foldw_k(const float* __restrict__ W, int ldW,
                        const float* __restrict__ bias,
                        const float* __restrict__ g, const float* __restrict__ bb,
                        const float* __restrict__ m, const float* __restrict__ v,
                        unsigned short* __restrict__ Wb, float* __restrict__ biasF,
                        int O, int Opad, int K) {
  long i = (long)blockIdx.x * 256 + threadIdx.x;
  if (i >= (long)Opad * K) return;
  int o = (int)(i / K), k = (int)(i % K);
  float sc = 1.f, sh = 0.f;
  if (o < O && g) { sc = g[o] * rsqrtf(v[o] + BN_EPS); sh = bb[o] - m[o] * sc; }
  float w = (o < O) ? W[(long)o * ldW + k] * sc : 0.f;
  Wb[i] = f2bf(w);
  if (k == 0 && biasF) {
    float bf = 0.f;
    if (o < O) bf = (bias ? bias[o] : 0.f) * sc + sh;
    biasF[o] = bf;
  }
}

// ---------------------------------------------------------------------------
// conv1 (3->128) + bn + relu -> bf16 token-major. grid (N, g), block 128
// ---------------------------------------------------------------------------
__global__ void conv1_k(const float* __restrict__ x, const float* __restrict__ w1,
                        const float* __restrict__ g, const float* __restrict__ bb,
                        const float* __restrict__ m, const float* __restrict__ v,
                        unsigned short* __restrict__ h0b) {
  int o = threadIdx.x, n = blockIdx.x, b = blockIdx.y;
  const float* xb = x + (long)b * 3 * N_;
  float val = w1[o * 3 + 0] * xb[n] + w1[o * 3 + 1] * xb[N_ + n] + w1[o * 3 + 2] * xb[2 * N_ + n];
  float sc = g[o] * rsqrtf(v[o] + BN_EPS);
  val = val * sc + (bb[o] - m[o] * sc);
  h0b[((long)b * N_ + n) * D_ + o] = f2bf(fmaxf(val, 0.f));
}

// ---------------------------------------------------------------------------
// Token-output MFMA GEMM (swapped operands): out[n][o] bf16, O mult of 128.
// Tile TM x 128, BK=64, block 256 (2x2 waves). DMA staging + XOR swizzle.
// Epilogue: LDS repack -> 256B-row vector stores.
// flags: 16 add bf16 res after act | 32 pool partials
// ---------------------------------------------------------------------------
template <int TM>
__global__ __launch_bounds__(256, 4)
void gemm_tok(const unsigned short* __restrict__ Wb, int ldW,
              const unsigned short* __restrict__ A, long sA, int ldA,
              const float* __restrict__ biasF,
              const float* __restrict__ perBO, int ldPBO,
              const unsigned short* __restrict__ resH, long sRes, int ldRes,
              unsigned short* __restrict__ outH, long sOutH, int ldOutH,
              float* __restrict__ pmax, float* __restrict__ psum,
              int K, int act, int flags) {
  constexpr int MT = TM / 32;
  __shared__ unsigned short lAB[TM * 64 + 128 * 64];
  __shared__ float lpm[4][64], lps[4][64];
  unsigned short* lA = lAB;
  unsigned short* lB = lAB + TM * 64;
  unsigned short* lS = lAB;                 // repack tile TM x 128 (aliases)
  int tid = threadIdx.x;
  int n0 = blockIdx.x * TM, o0 = blockIdx.y * 128, b = blockIdx.z;
  int wave = tid >> 6, lane = tid & 63;
  int wr = wave >> 1, wc = wave & 1;
  int quad = lane >> 4, l15 = lane & 15;
  int rowL = lane >> 3;
  int kseg = (lane & 7) ^ rowL;
  const unsigned short* Ab = A + (long)b * sA + (long)n0 * ldA;
  const unsigned short* Wp = Wb + (long)o0 * ldW;

  f32x4 acc[MT][4];
  #pragma unroll
  for (int i = 0; i < MT; ++i)
    #pragma unroll
    for (int j = 0; j < 4; ++j) acc[i][j] = (f32x4){0.f, 0.f, 0.f, 0.f};

  for (int kc = 0; kc < K; kc += 64) {
    #pragma unroll
    for (int t = 0; t < 4; ++t) {
      int chunk = t * 4 + wave;
      dma16(Wp + (long)(chunk * 8 + rowL) * ldW + kc + kseg * 8, &lB[chunk * 512]);
      if (chunk < TM / 8)
        dma16(Ab + (long)(chunk * 8 + rowL) * ldA + kc + kseg * 8, &lA[chunk * 512]);
    }
    __syncthreads();
    #pragma unroll
    for (int kk = 0; kk < 2; ++kk) {
      short8 af[MT], bf[4];
      #pragma unroll
      for (int mt = 0; mt < MT; ++mt) {
        int r = wr * (TM / 2) + mt * 16 + l15;
        af[mt] = *(const short8*)&lA[r * 64 + (((kk * 4 + quad) ^ (l15 & 7)) * 8)];
      }
      #pragma unroll
      for (int ot = 0; ot < 4; ++ot) {
        int r = wc * 64 + ot * 16 + l15;
        bf[ot] = *(const short8*)&lB[r * 64 + (((kk * 4 + quad) ^ (l15 & 7)) * 8)];
      }
      #pragma unroll
      for (int mt = 0; mt < MT; ++mt)
        #pragma unroll
        for (int ot = 0; ot < 4; ++ot)
          acc[mt][ot] = __builtin_amdgcn_mfma_f32_16x16x32_bf16(bf[ot], af[mt], acc[mt][ot], 0, 0, 0);
    }
    __syncthreads();
  }

  bool doPool = (flags & 32) != 0;
  #pragma unroll
  for (int ot = 0; ot < 4; ++ot) {
    int obL = wc * 64 + ot * 16 + quad * 4;
    int ob = o0 + obL;
    float bi[4] = {0.f, 0.f, 0.f, 0.f};
    if (biasF) { float4 t = *(const float4*)&biasF[ob]; bi[0] = t.x; bi[1] = t.y; bi[2] = t.z; bi[3] = t.w; }
    if (perBO) {
      float4 t = *(const float4*)&perBO[(long)b * ldPBO + ob];
      bi[0] += t.x; bi[1] += t.y; bi[2] += t.z; bi[3] += t.w;
    }
    float pm4[4], ps4[4];
    #pragma unroll
    for (int r = 0; r < 4; ++r) { pm4[r] = -1e30f; ps4[r] = 0.f; }
    int g = obL >> 3, go = obL & 7;
    #pragma unroll
    for (int mt = 0; mt < MT; ++mt) {
      int nL = wr * (TM / 2) + mt * 16 + l15;
      float vals[4];
      #pragma unroll
      for (int r = 0; r < 4; ++r) {
        float val = acc[mt][ot][r] + bi[r];
        if (act == 1)      val = fmaxf(val, 0.f);
        else if (act == 2) val = (val >= 0.f) ? val : 0.2f * val;
        vals[r] = val;
      }
      if (flags & 16) {
        uint2 rv = *(const uint2*)&resH[(long)b * sRes + (long)(n0 + nL) * ldRes + ob];
        unsigned short rr[4];
        *(uint2*)rr = rv;
        #pragma unroll
        for (int r = 0; r < 4; ++r) vals[r] += bf2f(rr[r]);
      }
      unsigned short t4[4];
      #pragma unroll
      for (int r = 0; r < 4; ++r) {
        t4[r] = f2bf(vals[r]);
        if (doPool) { pm4[r] = fmaxf(pm4[r], vals[r]); ps4[r] += vals[r]; }
      }
      int gp = (g & 8) | ((g ^ (nL & 7)) & 7);
      *(uint2*)&lS[nL * 128 + gp * 8 + go] = *(uint2*)&t4[0];
    }
    if (doPool) {
      #pragma unroll
      for (int r = 0; r < 4; ++r) {
        float m = pm4[r], s = ps4[r];
        m = fmaxf(m, __shfl_xor(m, 1)); s += __shfl_xor(s, 1);
        m = fmaxf(m, __shfl_xor(m, 2)); s += __shfl_xor(s, 2);
        m = fmaxf(m, __shfl_xor(m, 4)); s += __shfl_xor(s, 4);
        m = fmaxf(m, __shfl_xor(m, 8)); s += __shfl_xor(s, 8);
        if (l15 == 0) { lpm[wave][ot * 16 + quad * 4 + r] = m; lps[wave][ot * 16 + quad * 4 + r] = s; }
      }
    }
  }
  __syncthreads();
  {
    int r0 = tid >> 4, s = tid & 15;
    #pragma unroll
    for (int it = 0; it < TM / 16; ++it) {
      int row = it * 16 + r0;
      int sp = (s & 8) | ((s ^ (row & 7)) & 7);
      short8 v = *(const short8*)&lS[row * 128 + sp * 8];
      *(short8*)&outH[(long)b * sOutH + (long)(n0 + row) * ldOutH + o0 + s * 8] = v;
    }
  }
  if (doPool && tid < 128) {
    int wcx = tid >> 6, ol = tid & 63;
    float m = fmaxf(lpm[wcx][ol], lpm[wcx + 2][ol]);
    float s = lps[wcx][ol] + lps[wcx + 2][ol];
    int o = o0 + wcx * 64 + ol;
    pmax[((long)b * 16 + blockIdx.x) * 1024 + o] = m;
    psum[((long)b * 16 + blockIdx.x) * 1024 + o] = s;
  }
}

// ---------------------------------------------------------------------------
// Channel-output MFMA GEMM (unswapped): out[o][n] fp32 or bf16; O guarded.
// ---------------------------------------------------------------------------
template <int TM>
__global__ __launch_bounds__(256, 4)
void gemm_chan(const unsigned short* __restrict__ Wb, int ldW,
               const unsigned short* __restrict__ A, long sA, int ldA,
               const float* __restrict__ biasF,
               float* __restrict__ outF, long sOutF, int ldOutF,
               unsigned short* __restrict__ outH, long sOutH, int ldOutH,
               int K, int O, int act) {
  constexpr int MT = TM / 32;
  __shared__ unsigned short lA[TM * 64];
  __shared__ unsigned short lB[128 * 64];
  int tid = threadIdx.x;
  int n0 = blockIdx.x * TM, o0 = blockIdx.y * 128, b = blockIdx.z;
  int wave = tid >> 6, lane = tid & 63;
  int wr = wave >> 1, wc = wave & 1;
  int quad = lane >> 4, l15 = lane & 15;
  int rowL = lane >> 3;
  int kseg = (lane & 7) ^ rowL;
  const unsigned short* Ab = A + (long)b * sA + (long)n0 * ldA;
  const unsigned short* Wp = Wb + (long)o0 * ldW;

  f32x4 acc[MT][4];
  #pragma unroll
  for (int i = 0; i < MT; ++i)
    #pragma unroll
    for (int j = 0; j < 4; ++j) acc[i][j] = (f32x4){0.f, 0.f, 0.f, 0.f};

  for (int kc = 0; kc < K; kc += 64) {
    #pragma unroll
    for (int t = 0; t < 4; ++t) {
      int chunk = t * 4 + wave;
      dma16(Wp + (long)(chunk * 8 + rowL) * ldW + kc + kseg * 8, &lB[chunk * 512]);
      if (chunk < TM / 8)
        dma16(Ab + (long)(chunk * 8 + rowL) * ldA + kc + kseg * 8, &lA[chunk * 512]);
    }
    __syncthreads();
    #pragma unroll
    for (int kk = 0; kk < 2; ++kk) {
      short8 af[MT], bf[4];
      #pragma unroll
      for (int mt = 0; mt < MT; ++mt) {
        int r = wr * (TM / 2) + mt * 16 + l15;
        af[mt] = *(const short8*)&lA[r * 64 + (((kk * 4 + quad) ^ (l15 & 7)) * 8)];
      }
      #pragma unroll
      for (int ot = 0; ot < 4; ++ot) {
        int r = wc * 64 + ot * 16 + l15;
        bf[ot] = *(const short8*)&lB[r * 64 + (((kk * 4 + quad) ^ (l15 & 7)) * 8)];
      }
      #pragma unroll
      for (int mt = 0; mt < MT; ++mt)
        #pragma unroll
        for (int ot = 0; ot < 4; ++ot)
          acc[mt][ot] = __builtin_amdgcn_mfma_f32_16x16x32_bf16(af[mt], bf[ot], acc[mt][ot], 0, 0, 0);
    }
    __syncthreads();
  }

  #pragma unroll
  for (int ot = 0; ot < 4; ++ot) {
    int o = o0 + wc * 64 + ot * 16 + l15;
    if (o >= O) continue;
    float bi = biasF ? biasF[o] : 0.f;
    #pragma unroll
    for (int mt = 0; mt < MT; ++mt) {
      int nb = n0 + wr * (TM / 2) + mt * 16 + quad * 4;
      float vals[4];
      #pragma unroll
      for (int r = 0; r < 4; ++r) {
        float val = acc[mt][ot][r] + bi;
        if (act == 1)      val = fmaxf(val, 0.f);
        else if (act == 2) val = (val >= 0.f) ? val : 0.2f * val;
        vals[r] = val;
      }
      if (outF)
        *(float4*)&outF[(long)b * sOutF + (long)o * ldOutF + nb] = *(float4*)vals;
      if (outH) {
        unsigned short t[4];
        #pragma unroll
        for (int r = 0; r < 4; ++r) t[r] = f2bf(vals[r]);
        *(uint2*)&outH[(long)b * sOutH + (long)o * ldOutH + nb] = *(uint2*)&t[0];
      }
    }
  }
}

// ---------------------------------------------------------------------------
// Gram row-stats -> lw[n] = mx[n] + log(rs[n]).  E = xk xk^T, K=128.
// grid (g, 32): b fastest -> XCD = b%8. Double-buffered LDS, 1 barrier/chunk,
// batched online-softmax update.
// ---------------------------------------------------------------------------
__global__ __launch_bounds__(256)
void gram_lw(const unsigned short* __restrict__ xk, long sXk,
             float* __restrict__ lw) {
  __shared__ unsigned short lK[2][64 * 128];
  int tid = threadIdx.x, wave = tid >> 6, lane = tid & 63;
  int quad = lane >> 4, l15 = lane & 15;
  int rowL4 = lane >> 4, s16 = lane & 15;
  int n0 = blockIdx.y * 64, b = blockIdx.x;
  const unsigned short* Kp = xk + (long)b * sXk;
  short8 afr[4];
  {
    const unsigned short* arow = Kp + (long)(n0 + wave * 16 + l15) * 128;
    #pragma unroll
    for (int kf = 0; kf < 4; ++kf) afr[kf] = *(const short8*)(arow + kf * 32 + quad * 8);
  }
  float runm[4], runs[4];
  #pragma unroll
  for (int r = 0; r < 4; ++r) { runm[r] = -1e30f; runs[r] = 0.f; }

  auto stage = [&](int ch, int bf) {
    #pragma unroll
    for (int t = 0; t < 4; ++t) {
      int c = t * 4 + wave;
      int row = c * 4 + rowL4;
      int gseg = (s16 & 8) | ((s16 ^ (row & 7)) & 7);
      dma16(Kp + (long)(ch * 64 + row) * 128 + gseg * 8, &lK[bf][c * 512]);
    }
  };
  stage(0, 0);

  for (int ch = 0; ch < 32; ++ch) {
    __syncthreads();
    int bf = ch & 1;
    if (ch + 1 < 32) stage(ch + 1, bf ^ 1);
    f32x4 sv[4];
    #pragma unroll
    for (int mf = 0; mf < 4; ++mf) {
      f32x4 s = (f32x4){0.f, 0.f, 0.f, 0.f};
      #pragma unroll
      for (int kf = 0; kf < 4; ++kf) {
        int r = mf * 16 + l15, q = kf * 4 + quad;
        int sp = (q & 8) | ((q ^ (r & 7)) & 7);
        short8 bfr = *(const short8*)&lK[bf][r * 128 + sp * 8];
        s = __builtin_amdgcn_mfma_f32_16x16x32_bf16(afr[kf], bfr, s, 0, 0, 0);
      }
      sv[mf] = s;
    }
    #pragma unroll
    for (int r = 0; r < 4; ++r) {
      float e0 = sv[0][r], e1 = sv[1][r], e2 = sv[2][r], e3 = sv[3][r];
      float cm = fmaxf(fmaxf(e0, e1), fmaxf(e2, e3));
      float mn = fmaxf(runm[r], cm);
      runs[r] = runs[r] * __expf(runm[r] - mn) +
                (__expf(e0 - mn) + __expf(e1 - mn)) + (__expf(e2 - mn) + __expf(e3 - mn));
      runm[r] = mn;
    }
  }
  #pragma unroll
  for (int r = 0; r < 4; ++r) {
    float m = runm[r], s = runs[r];
    #pragma unroll
    for (int off = 1; off < 16; off <<= 1) {
      float mo = __shfl_xor(m, off), so = __shfl_xor(s, off);
      float mn = fmaxf(m, mo);
      s = s * __expf(m - mn) + so * __expf(mo - mn);
      m = mn;
    }
    if (l15 == 0) {
      int n = n0 + wave * 16 + quad * 4 + r;
      lw[(long)b * 2048 + n] = m + __logf(s);
    }
  }
}

// ---------------------------------------------------------------------------
// Fused PV, no lP LDS round-trip:
//   S_T = mfma(K_frag, Q_frag): lane holds p[m=l15][n=quad*4+r] packed bf16.
//   PV A-frags assembled via 4 __shfl per kc (in-register transpose).
//   cs[m] per-lane (m=l15), cross-quad shfl reduce.
// grid (g, 32): b fastest. Double-buffered K/V, one barrier per chunk.
// ---------------------------------------------------------------------------
__global__ __launch_bounds__(256)
void pv_k(const unsigned short* __restrict__ xk, long sXk,
          const unsigned short* __restrict__ xv, long sXv,
          const float* __restrict__ lw,
          const unsigned short* __restrict__ lib, long sLi, int ldLi,
          unsigned short* __restrict__ xrb, long sXr) {
  __shared__ unsigned short lK[2][64 * 128];
  __shared__ unsigned short lV[2][128 * 64];
  __shared__ float lwt[2][64];
  int tid = threadIdx.x, wave = tid >> 6, lane = tid & 63;
  int quad = lane >> 4, l15 = lane & 15;
  int rowL4 = lane >> 4, s16 = lane & 15;
  int rowL8 = lane >> 3, s8 = lane & 7;
  int m0 = blockIdx.y * 64, b = blockIdx.x;
  const unsigned short* Kp = xk + (long)b * sXk;
  const unsigned short* Vp = xv + (long)b * sXv;
  short8 akr[4];
  {
    const unsigned short* arow = Kp + (long)(m0 + wave * 16 + l15) * 128;
    #pragma unroll
    for (int kf = 0; kf < 4; ++kf) akr[kf] = *(const short8*)(arow + kf * 32 + quad * 8);
  }
  f32x4 acc[8];
  #pragma unroll
  for (int dt = 0; dt < 8; ++dt) acc[dt] = (f32x4){0.f, 0.f, 0.f, 0.f};
  float runc = 0.f;

  auto stage = [&](int ch, int bf) {
    #pragma unroll
    for (int t = 0; t < 4; ++t) {
      int c = t * 4 + wave;
      int rowK = c * 4 + rowL4;
      int gsegK = (s16 & 8) | ((s16 ^ (rowK & 7)) & 7);
      dma16(Kp + (long)(ch * 64 + rowK) * 128 + gsegK * 8, &lK[bf][c * 512]);
      int rowV = c * 8 + rowL8;
      int gsegV = s8 ^ (rowV & 7);
      dma16(Vp + (long)rowV * 2048 + ch * 64 + gsegV * 8, &lV[bf][c * 512]);
    }
    if (tid < 64) lwt[bf][tid] = lw[(long)b * 2048 + ch * 64 + tid];
  };
  stage(0, 0);

  for (int ch = 0; ch < 32; ++ch) {
    __syncthreads();
    int bf = ch & 1;
    if (ch + 1 < 32) stage(ch + 1, bf ^ 1);
    // S_T: lane holds p[m=l15][n = ch*64 + nf*16 + quad*4 + r], packed bf16
    unsigned pd0[4], pd1[4];
    #pragma unroll
    for (int nf = 0; nf < 4; ++nf) {
      f32x4 s = (f32x4){0.f, 0.f, 0.f, 0.f};
      #pragma unroll
      for (int kf = 0; kf < 4; ++kf) {
        int r = nf * 16 + l15, q = kf * 4 + quad;
        int sp = (q & 8) | ((q ^ (r & 7)) & 7);
        short8 kfr = *(const short8*)&lK[bf][r * 128 + sp * 8];
        s = __builtin_amdgcn_mfma_f32_16x16x32_bf16(kfr, akr[kf], s, 0, 0, 0);
      }
      float4 lw4 = *(const float4*)&lwt[bf][nf * 16 + quad * 4];
      float lwv[4] = {lw4.x, lw4.y, lw4.z, lw4.w};
      unsigned short t4[4];
      #pragma unroll
      for (int r = 0; r < 4; ++r) {
        float p = __expf(s[r] - lwv[r]);
        runc += p;
        t4[r] = f2bf(p);
      }
      pd0[nf] = (unsigned)t4[0] | ((unsigned)t4[1] << 16);
      pd1[nf] = (unsigned)t4[2] | ((unsigned)t4[3] << 16);
    }
    // PV: A-frag via in-register transpose (4 shfls per kc)
    #pragma unroll
    for (int kc = 0; kc < 2; ++kc) {
      unsigned d0 = (quad >= 2) ? pd0[2 * kc + 1] : pd0[2 * kc];
      unsigned d1 = (quad >= 2) ? pd1[2 * kc + 1] : pd1[2 * kc];
      int s0 = ((quad & 1) << 5) + l15;
      union { unsigned u[4]; short8 v; } pu;
      pu.u[0] = (unsigned)__shfl((int)d0, s0);
      pu.u[1] = (unsigned)__shfl((int)d1, s0);
      pu.u[2] = (unsigned)__shfl((int)d0, s0 + 16);
      pu.u[3] = (unsigned)__shfl((int)d1, s0 + 16);
      short8 pa = pu.v;
      #pragma unroll
      for (int dt = 0; dt < 8; ++dt) {
        int r = dt * 16 + l15;
        int spv = (kc * 4 + quad) ^ (r & 7);
        short8 vb = *(const short8*)&lV[bf][r * 64 + spv * 8];
        acc[dt] = __builtin_amdgcn_mfma_f32_16x16x32_bf16(pa, vb, acc[dt], 0, 0, 0);
      }
    }
  }
  // colsum per m=l15: reduce over quads
  float s = runc;
  s += __shfl_xor(s, 16);
  s += __shfl_xor(s, 32);
  float inv = 1.f / (1e-9f + s);
  float inv4[4];
  #pragma unroll
  for (int r = 0; r < 4; ++r) inv4[r] = __shfl(inv, quad * 4 + r);
  #pragma unroll
  for (int dt = 0; dt < 8; ++dt) {
    int d = dt * 16 + l15;
    #pragma unroll
    for (int r = 0; r < 4; ++r) {
      int m = m0 + wave * 16 + quad * 4 + r;
      float lv = bf2f(lib[(long)b * sLi + (long)m * ldLi + d]);
      xrb[(long)b * sXr + (long)m * 128 + d] = f2bf(lv - acc[dt][r] * inv4[r]);
    }
  }
}

// ---------------------------------------------------------------------------
__global__ void poolred_k(const float* __restrict__ pmax, const float* __restrict__ psum,
                          float* __restrict__ xmax, float* __restrict__ xavg) {
  int f = blockIdx.x * 256 + threadIdx.x, b = blockIdx.y;
  float mx = -1e30f, s = 0.f;
  #pragma unroll
  for (int t = 0; t < 16; ++t) {
    mx = fmaxf(mx, pmax[((long)b * 16 + t) * 1024 + f]);
    s += psum[((long)b * 16 + t) * 1024 + f];
  }
  xmax[(long)b * 1024 + f] = mx;
  xavg[(long)b * 1024 + f] = s * (1.f / 2048.f);
}

// pt[b][o] = sc1[o] * ( ws1[o][1024:2048].xmax + ws1[o][2048:3072].xavg )
__global__ __launch_bounds__(256)
void poolterm_k(const float* __restrict__ ws1, const float* __restrict__ xmax,
                const float* __restrict__ xavg,
                const float* __restrict__ bg, const float* __restrict__ bv,
                float* __restrict__ pt) {
  int o = blockIdx.x, b = blockIdx.y, tid = threadIdx.x;
  const float* w = ws1 + (long)o * 3072;
  float s = 0.f;
  #pragma unroll
  for (int it = 0; it < 4; ++it) {
    int c = tid + it * 256;
    s += w[1024 + c] * xmax[(long)b * 1024 + c] + w[2048 + c] * xavg[(long)b * 1024 + c];
  }
  #pragma unroll
  for (int off = 32; off; off >>= 1) s += __shfl_xor(s, off);
  __shared__ float rsm[4];
  if ((tid & 63) == 0) rsm[tid >> 6] = s;
  __syncthreads();
  if (tid == 0) {
    float sc = bg[o] * rsqrtf(bv[o] + BN_EPS);
    pt[(long)b * H1_ + o] = sc * (rsm[0] + rsm[1] + rsm[2] + rsm[3]);
  }
}

// ---------------------------------------------------------------------------
extern "C" void kernel_launch(void* const* d_in, const int* in_sizes, int n_in,
                              void* d_out, int out_size, void* d_ws, size_t ws_size,
                              hipStream_t stream) {
  const float* x      = (const float*)d_in[0];
  const float* w1     = (const float*)d_in[1];
  const float* w2     = (const float*)d_in[2];
  const float* bn1_g  = (const float*)d_in[3];
  const float* bn1_b  = (const float*)d_in[4];
  const float* bn1_m  = (const float*)d_in[5];
  const float* bn1_v  = (const float*)d_in[6];
  const float* bn2_g  = (const float*)d_in[7];
  const float* bn2_b  = (const float*)d_in[8];
  const float* bn2_m  = (const float*)d_in[9];
  const float* bn2_v  = (const float*)d_in[10];
  const float* sa_wqk = (const float*)d_in[11];
  const float* sa_wv  = (const float*)d_in[12];
  const float* sa_bv  = (const float*)d_in[13];
  const float* sa_wt  = (const float*)d_in[14];
  const float* sa_bt  = (const float*)d_in[15];
  const float* sa_g   = (const float*)d_in[16];
  const float* sa_b   = (const float*)d_in[17];
  const float* sa_m   = (const float*)d_in[18];
  const float* sa_v   = (const float*)d_in[19];
  const float* wf     = (const float*)d_in[20];
  const float* bnf_g  = (const float*)d_in[21];
  const float* bnf_b  = (const float*)d_in[22];
  const float* bnf_m  = (const float*)d_in[23];
  const float* bnf_v  = (const float*)d_in[24];
  const float* ws1    = (const float*)d_in[25];
  const float* bs1    = (const float*)d_in[26];
  const float* bns1_g = (const float*)d_in[27];
  const float* bns1_b = (const float*)d_in[28];
  const float* bns1_m = (const float*)d_in[29];
  const float* bns1_v = (const float*)d_in[30];
  const float* ws2    = (const float*)d_in[31];
  const float* bs2    = (const float*)d_in[32];
  const float* bns2_g = (const float*)d_in[33];
  const float* bns2_b = (const float*)d_in[34];
  const float* bns2_m = (const float*)d_in[35];
  const float* bns2_v = (const float*)d_in[36];
  float* out = (float*)d_out;

  float* ws = (float*)d_ws;
  size_t off = 0;
  auto alloc  = [&](size_t n) { float* p = ws + off; off += (n + 63) & ~(size_t)63; return p; };
  auto allocH = [&](size_t n) { return (unsigned short*)alloc((n + 1) / 2); };

  unsigned short* w2b  = allocH(128 * 128);
  unsigned short* wqkb = allocH(4 * 128 * 128);
  unsigned short* wvb  = allocH(4 * 128 * 128);
  unsigned short* wtb  = allocH(4 * 128 * 128);
  unsigned short* wfb  = allocH((size_t)F_ * 512);
  unsigned short* ws1b = allocH((size_t)H1_ * 1024);
  unsigned short* ws2b = allocH((size_t)128 * 512);
  float* bias_w2 = alloc(128);
  float* bias_v  = alloc(512);
  float* bias_t  = alloc(512);
  float* bias_f  = alloc(1024);
  float* bias_s1 = alloc(512);
  float* bias_s2 = alloc(128);
  float* lwB  = alloc((size_t)16 * 2048);
  float* pmax = alloc((size_t)16 * 16 * 1024);
  float* psum = alloc((size_t)16 * 16 * 1024);
  float* xmaxB = alloc((size_t)16 * 1024);
  float* xavgB = alloc((size_t)16 * 1024);
  float* ptB   = alloc((size_t)16 * 512);
  size_t fixedOff = off;

  // per-batch (floats): h1b 131072 + featsb 524288 + fusedb 1048576 +
  //                     xkb 131072 + xvb 131072 + xrb 131072
  const size_t perB = 131072 + 524288 + 1048576 + 131072 + 131072 + 131072;
  size_t wsFloats = ws_size / 4;
  int Gb = 1;
  for (int c : {16, 8, 4, 2, 1}) {
    if (fixedOff + (size_t)c * perB + 4096 <= wsFloats) { Gb = c; break; }
  }

  unsigned short* h1b    = allocH((size_t)Gb * 262144);
  unsigned short* featsb = allocH((size_t)Gb * 1048576);   // hs1b aliases
  unsigned short* fusedb = allocH((size_t)Gb * 2097152);
  unsigned short* xkb    = allocH((size_t)Gb * 262144);
  unsigned short* xvb    = allocH((size_t)Gb * 262144);
  unsigned short* xrb    = allocH((size_t)Gb * 262144);    // h0b aliases
  unsigned short* h0b  = xrb;
  unsigned short* hs1b = featsb;

  foldw_k<<<64, 256, 0, stream>>>(w2, 128, nullptr, bn2_g, bn2_b, bn2_m, bn2_v,
                                  w2b, bias_w2, 128, 128, 128);
  for (int i = 0; i < 4; ++i) {
    foldw_k<<<64, 256, 0, stream>>>(sa_wqk + (size_t)i * 16384, 128, nullptr,
                                    nullptr, nullptr, nullptr, nullptr,
                                    wqkb + (size_t)i * 16384, nullptr, 128, 128, 128);
    foldw_k<<<64, 256, 0, stream>>>(sa_wv + (size_t)i * 16384, 128, sa_bv + i * 128,
                                    nullptr, nullptr, nullptr, nullptr,
                                    wvb + (size_t)i * 16384, bias_v + i * 128, 128, 128, 128);
    foldw_k<<<64, 256, 0, stream>>>(sa_wt + (size_t)i * 16384, 128, sa_bt + i * 128,
                                    sa_g + i * 128, sa_b + i * 128, sa_m + i * 128, sa_v + i * 128,
                                    wtb + (size_t)i * 16384, bias_t + i * 128, 128, 128, 128);
  }
  foldw_k<<<2048, 256, 0, stream>>>(wf, 512, nullptr, bnf_g, bnf_b, bnf_m, bnf_v,
                                    wfb, bias_f, 1024, 1024, 512);
  foldw_k<<<2048, 256, 0, stream>>>(ws1, 3072, bs1, bns1_g, bns1_b, bns1_m, bns1_v,
                                    ws1b, bias_s1, 512, 512, 1024);
  foldw_k<<<256, 256, 0, stream>>>(ws2, 512, bs2, bns2_g, bns2_b, bns2_m, bns2_v,
                                   ws2b, bias_s2, 50, 128, 512);

  const long sAct = 262144, sFeat = 1048576, sFus = 2097152;
  for (int b0 = 0; b0 < B_; b0 += Gb) {
    int g = Gb;
    conv1_k<<<dim3(N_, g), 128, 0, stream>>>(x + (long)b0 * 3 * N_, w1,
                                             bn1_g, bn1_b, bn1_m, bn1_v, h0b);
    // conv2+bn2+relu -> h1b bf16
    gemm_tok<64><<<dim3(32, 1, g), 256, 0, stream>>>(
        w2b, 128, h0b, sAct, 128, bias_w2, nullptr, 0, nullptr, 0, 0,
        h1b, sAct, 128, nullptr, nullptr, 128, 1, 0);

    for (int i = 0; i < 4; ++i) {
      const unsigned short* lib = (i == 0) ? h1b : featsb + (size_t)(i - 1) * 128;
      int ldLi = (i == 0) ? 128 : 512;
      long sLi = (i == 0) ? sAct : sFeat;
      // xk (bf16 token)
      gemm_tok<64><<<dim3(32, 1, g), 256, 0, stream>>>(
          wqkb + (size_t)i * 16384, 128, lib, sLi, ldLi, nullptr, nullptr, 0,
          nullptr, 0, 0, xkb, sAct, 128, nullptr, nullptr, 128, 0, 0);
      // xv (bf16 channel, +bv)
      gemm_chan<64><<<dim3(32, 1, g), 256, 0, stream>>>(
          wvb + (size_t)i * 16384, 128, lib, sLi, ldLi, bias_v + i * 128,
          nullptr, 0, 0, xvb, sAct, 2048, 128, 128, 0);
      gram_lw<<<dim3(g, 32), 256, 0, stream>>>(xkb, sAct, lwB);
      pv_k<<<dim3(g, 32), 256, 0, stream>>>(xkb, sAct, xvb, sAct, lwB,
                                            lib, sLi, ldLi, xrb, sAct);
      // feats_i = li + relu(wt' @ (li - xr) + bt')   (res = bf16 li)
      gemm_tok<64><<<dim3(32, 1, g), 256, 0, stream>>>(
          wtb + (size_t)i * 16384, 128, xrb, sAct, 128, bias_t + i * 128, nullptr, 0,
          lib, sLi, ldLi,
          featsb + (size_t)i * 128, sFeat, 512, nullptr, nullptr, 128, 1, 16);
    }

    // fused = leaky(wf' @ feats + bf') -> bf16 + pool partials
    gemm_tok<128><<<dim3(16, 8, g), 256, 0, stream>>>(
        wfb, 512, featsb, sFeat, 512, bias_f, nullptr, 0, nullptr, 0, 0,
        fusedb, sFus, 1024, pmax, psum, 512, 2, 32);
    poolred_k<<<dim3(4, g), 256, 0, stream>>>(pmax, psum, xmaxB, xavgB);
    poolterm_k<<<dim3(512, g), 256, 0, stream>>>(ws1, xmaxB, xavgB, bns1_g, bns1_v, ptB);
    // hs1 = relu(ws1' @ fused + bs1' + pt) -> bf16
    gemm_tok<128><<<dim3(16, 4, g), 256, 0, stream>>>(
        ws1b, 1024, fusedb, sFus, 1024, bias_s1, ptB, 512, nullptr, 0, 0,
        hs1b, sFeat, 512, nullptr, nullptr, 1024, 1, 0);
    // out = relu(ws2' @ hs1 + bs2') -> fp32 channel-major
    gemm_chan<64><<<dim3(32, 1, g), 256, 0, stream>>>(
        ws2b, 512, hs1b, sFeat, 512, bias_s2,
        out + (long)b0 * OUT_ * N_, (long)OUT_ * N_, 2048, nullptr, 0, 0,
        512, 50, 1);
  }
}

// Round 12
// 785.997 us; speedup vs baseline: 1.4074x; 1.0025x over previous
//
#include <hip/hip_runtime.h>
#include <cstdint>
#include <cstddef>

#define B_   16
#define N_   2048
#define D_   128
#define F_   1024
#define H1_  512
#define OUT_ 50

static constexpr float BN_EPS = 1e-5f;

typedef __attribute__((ext_vector_type(8))) short short8;
typedef __attribute__((ext_vector_type(4))) float f32x4;

__device__ inline unsigned short f2bf(float f) {
  union { float f; unsigned u; } v; v.f = f;
  unsigned r = v.u + 0x7fff + ((v.u >> 16) & 1);
  return (unsigned short)(r >> 16);
}
__device__ inline float bf2f(unsigned short h) {
  union { unsigned u; float f; } v; v.u = ((unsigned)h) << 16; return v.f;
}

// async global->LDS, 16B per lane; LDS dest = wave-uniform base + lane*16
__device__ inline void dma16(const unsigned short* g, unsigned short* l) {
  __builtin_amdgcn_global_load_lds(
      (const __attribute__((address_space(1))) unsigned int*)g,
      (__attribute__((address_space(3))) unsigned int*)l, 16, 0, 0);
}

// ---------------------------------------------------------------------------
// Fold BN (+bias) into bf16 weights + fp32 bias.
// ---------------------------------------------------------------------------
__global__ void foldw_k(const float* __restrict__ W, int ldW,
                        const float* __restrict__ bias,
                        const float* __restrict__ g, const float* __restrict__ bb,
                        const float* __restrict__ m, const float* __restrict__ v,
                        unsigned short* __restrict__ Wb, float* __restrict__ biasF,
                        int O, int Opad, int K) {
  long i = (long)blockIdx.x * 256 + threadIdx.x;
  if (i >= (long)Opad * K) return;
  int o = (int)(i / K), k = (int)(i % K);
  float sc = 1.f, sh = 0.f;
  if (o < O && g) { sc = g[o] * rsqrtf(v[o] + BN_EPS); sh = bb[o] - m[o] * sc; }
  float w = (o < O) ? W[(long)o * ldW + k] * sc : 0.f;
  Wb[i] = f2bf(w);
  if (k == 0 && biasF) {
    float bf = 0.f;
    if (o < O) bf = (bias ? bias[o] : 0.f) * sc + sh;
    biasF[o] = bf;
  }
}

// ---------------------------------------------------------------------------
// conv1 (3->128) + bn + relu -> bf16 token-major. grid (N, g), block 128
// ---------------------------------------------------------------------------
__global__ void conv1_k(const float* __restrict__ x, const float* __restrict__ w1,
                        const float* __restrict__ g, const float* __restrict__ bb,
                        const float* __restrict__ m, const float* __restrict__ v,
                        unsigned short* __restrict__ h0b) {
  int o = threadIdx.x, n = blockIdx.x, b = blockIdx.y;
  const float* xb = x + (long)b * 3 * N_;
  float val = w1[o * 3 + 0] * xb[n] + w1[o * 3 + 1] * xb[N_ + n] + w1[o * 3 + 2] * xb[2 * N_ + n];
  float sc = g[o] * rsqrtf(v[o] + BN_EPS);
  val = val * sc + (bb[o] - m[o] * sc);
  h0b[((long)b * N_ + n) * D_ + o] = f2bf(fmaxf(val, 0.f));
}

// ---------------------------------------------------------------------------
// Token-output MFMA GEMM (swapped operands): out[n][o] bf16, O mult of 128.
// Tile TM x 128, BK=64, block 256 (2x2 waves). DMA staging + XOR swizzle.
// Epilogue: LDS repack -> 256B-row vector stores.
// flags: 16 add bf16 res after act | 32 pool partials
// ---------------------------------------------------------------------------
template <int TM>
__global__ __launch_bounds__(256, 4)
void gemm_tok(const unsigned short* __restrict__ Wb, int ldW,
              const unsigned short* __restrict__ A, long sA, int ldA,
              const float* __restrict__ biasF,
              const float* __restrict__ perBO, int ldPBO,
              const unsigned short* __restrict__ resH, long sRes, int ldRes,
              unsigned short* __restrict__ outH, long sOutH, int ldOutH,
              float* __restrict__ pmax, float* __restrict__ psum,
              int K, int act, int flags) {
  constexpr int MT = TM / 32;
  __shared__ unsigned short lAB[TM * 64 + 128 * 64];
  __shared__ float lpm[4][64], lps[4][64];
  unsigned short* lA = lAB;
  unsigned short* lB = lAB + TM * 64;
  unsigned short* lS = lAB;                 // repack tile TM x 128 (aliases)
  int tid = threadIdx.x;
  int n0 = blockIdx.x * TM, o0 = blockIdx.y * 128, b = blockIdx.z;
  int wave = tid >> 6, lane = tid & 63;
  int wr = wave >> 1, wc = wave & 1;
  int quad = lane >> 4, l15 = lane & 15;
  int rowL = lane >> 3;
  int kseg = (lane & 7) ^ rowL;
  const unsigned short* Ab = A + (long)b * sA + (long)n0 * ldA;
  const unsigned short* Wp = Wb + (long)o0 * ldW;

  f32x4 acc[MT][4];
  #pragma unroll
  for (int i = 0; i < MT; ++i)
    #pragma unroll
    for (int j = 0; j < 4; ++j) acc[i][j] = (f32x4){0.f, 0.f, 0.f, 0.f};

  for (int kc = 0; kc < K; kc += 64) {
    #pragma unroll
    for (int t = 0; t < 4; ++t) {
      int chunk = t * 4 + wave;
      dma16(Wp + (long)(chunk * 8 + rowL) * ldW + kc + kseg * 8, &lB[chunk * 512]);
      if (chunk < TM / 8)
        dma16(Ab + (long)(chunk * 8 + rowL) * ldA + kc + kseg * 8, &lA[chunk * 512]);
    }
    __syncthreads();
    #pragma unroll
    for (int kk = 0; kk < 2; ++kk) {
      short8 af[MT], bf[4];
      #pragma unroll
      for (int mt = 0; mt < MT; ++mt) {
        int r = wr * (TM / 2) + mt * 16 + l15;
        af[mt] = *(const short8*)&lA[r * 64 + (((kk * 4 + quad) ^ (l15 & 7)) * 8)];
      }
      #pragma unroll
      for (int ot = 0; ot < 4; ++ot) {
        int r = wc * 64 + ot * 16 + l15;
        bf[ot] = *(const short8*)&lB[r * 64 + (((kk * 4 + quad) ^ (l15 & 7)) * 8)];
      }
      #pragma unroll
      for (int mt = 0; mt < MT; ++mt)
        #pragma unroll
        for (int ot = 0; ot < 4; ++ot)
          acc[mt][ot] = __builtin_amdgcn_mfma_f32_16x16x32_bf16(bf[ot], af[mt], acc[mt][ot], 0, 0, 0);
    }
    __syncthreads();
  }

  bool doPool = (flags & 32) != 0;
  #pragma unroll
  for (int ot = 0; ot < 4; ++ot) {
    int obL = wc * 64 + ot * 16 + quad * 4;
    int ob = o0 + obL;
    float bi[4] = {0.f, 0.f, 0.f, 0.f};
    if (biasF) { float4 t = *(const float4*)&biasF[ob]; bi[0] = t.x; bi[1] = t.y; bi[2] = t.z; bi[3] = t.w; }
    if (perBO) {
      float4 t = *(const float4*)&perBO[(long)b * ldPBO + ob];
      bi[0] += t.x; bi[1] += t.y; bi[2] += t.z; bi[3] += t.w;
    }
    float pm4[4], ps4[4];
    #pragma unroll
    for (int r = 0; r < 4; ++r) { pm4[r] = -1e30f; ps4[r] = 0.f; }
    int g = obL >> 3, go = obL & 7;
    #pragma unroll
    for (int mt = 0; mt < MT; ++mt) {
      int nL = wr * (TM / 2) + mt * 16 + l15;
      float vals[4];
      #pragma unroll
      for (int r = 0; r < 4; ++r) {
        float val = acc[mt][ot][r] + bi[r];
        if (act == 1)      val = fmaxf(val, 0.f);
        else if (act == 2) val = (val >= 0.f) ? val : 0.2f * val;
        vals[r] = val;
      }
      if (flags & 16) {
        uint2 rv = *(const uint2*)&resH[(long)b * sRes + (long)(n0 + nL) * ldRes + ob];
        unsigned short rr[4];
        *(uint2*)rr = rv;
        #pragma unroll
        for (int r = 0; r < 4; ++r) vals[r] += bf2f(rr[r]);
      }
      unsigned short t4[4];
      #pragma unroll
      for (int r = 0; r < 4; ++r) {
        t4[r] = f2bf(vals[r]);
        if (doPool) { pm4[r] = fmaxf(pm4[r], vals[r]); ps4[r] += vals[r]; }
      }
      int gp = (g & 8) | ((g ^ (nL & 7)) & 7);
      *(uint2*)&lS[nL * 128 + gp * 8 + go] = *(uint2*)&t4[0];
    }
    if (doPool) {
      #pragma unroll
      for (int r = 0; r < 4; ++r) {
        float m = pm4[r], s = ps4[r];
        m = fmaxf(m, __shfl_xor(m, 1)); s += __shfl_xor(s, 1);
        m = fmaxf(m, __shfl_xor(m, 2)); s += __shfl_xor(s, 2);
        m = fmaxf(m, __shfl_xor(m, 4)); s += __shfl_xor(s, 4);
        m = fmaxf(m, __shfl_xor(m, 8)); s += __shfl_xor(s, 8);
        if (l15 == 0) { lpm[wave][ot * 16 + quad * 4 + r] = m; lps[wave][ot * 16 + quad * 4 + r] = s; }
      }
    }
  }
  __syncthreads();
  {
    int r0 = tid >> 4, s = tid & 15;
    #pragma unroll
    for (int it = 0; it < TM / 16; ++it) {
      int row = it * 16 + r0;
      int sp = (s & 8) | ((s ^ (row & 7)) & 7);
      short8 v = *(const short8*)&lS[row * 128 + sp * 8];
      *(short8*)&outH[(long)b * sOutH + (long)(n0 + row) * ldOutH + o0 + s * 8] = v;
    }
  }
  if (doPool && tid < 128) {
    int wcx = tid >> 6, ol = tid & 63;
    float m = fmaxf(lpm[wcx][ol], lpm[wcx + 2][ol]);
    float s = lps[wcx][ol] + lps[wcx + 2][ol];
    int o = o0 + wcx * 64 + ol;
    pmax[((long)b * 16 + blockIdx.x) * 1024 + o] = m;
    psum[((long)b * 16 + blockIdx.x) * 1024 + o] = s;
  }
}

// ---------------------------------------------------------------------------
// Channel-output MFMA GEMM (unswapped): out[o][n] fp32 or bf16; O guarded.
// ---------------------------------------------------------------------------
template <int TM>
__global__ __launch_bounds__(256, 4)
void gemm_chan(const unsigned short* __restrict__ Wb, int ldW,
               const unsigned short* __restrict__ A, long sA, int ldA,
               const float* __restrict__ biasF,
               float* __restrict__ outF, long sOutF, int ldOutF,
               unsigned short* __restrict__ outH, long sOutH, int ldOutH,
               int K, int O, int act) {
  constexpr int MT = TM / 32;
  __shared__ unsigned short lA[TM * 64];
  __shared__ unsigned short lB[128 * 64];
  int tid = threadIdx.x;
  int n0 = blockIdx.x * TM, o0 = blockIdx.y * 128, b = blockIdx.z;
  int wave = tid >> 6, lane = tid & 63;
  int wr = wave >> 1, wc = wave & 1;
  int quad = lane >> 4, l15 = lane & 15;
  int rowL = lane >> 3;
  int kseg = (lane & 7) ^ rowL;
  const unsigned short* Ab = A + (long)b * sA + (long)n0 * ldA;
  const unsigned short* Wp = Wb + (long)o0 * ldW;

  f32x4 acc[MT][4];
  #pragma unroll
  for (int i = 0; i < MT; ++i)
    #pragma unroll
    for (int j = 0; j < 4; ++j) acc[i][j] = (f32x4){0.f, 0.f, 0.f, 0.f};

  for (int kc = 0; kc < K; kc += 64) {
    #pragma unroll
    for (int t = 0; t < 4; ++t) {
      int chunk = t * 4 + wave;
      dma16(Wp + (long)(chunk * 8 + rowL) * ldW + kc + kseg * 8, &lB[chunk * 512]);
      if (chunk < TM / 8)
        dma16(Ab + (long)(chunk * 8 + rowL) * ldA + kc + kseg * 8, &lA[chunk * 512]);
    }
    __syncthreads();
    #pragma unroll
    for (int kk = 0; kk < 2; ++kk) {
      short8 af[MT], bf[4];
      #pragma unroll
      for (int mt = 0; mt < MT; ++mt) {
        int r = wr * (TM / 2) + mt * 16 + l15;
        af[mt] = *(const short8*)&lA[r * 64 + (((kk * 4 + quad) ^ (l15 & 7)) * 8)];
      }
      #pragma unroll
      for (int ot = 0; ot < 4; ++ot) {
        int r = wc * 64 + ot * 16 + l15;
        bf[ot] = *(const short8*)&lB[r * 64 + (((kk * 4 + quad) ^ (l15 & 7)) * 8)];
      }
      #pragma unroll
      for (int mt = 0; mt < MT; ++mt)
        #pragma unroll
        for (int ot = 0; ot < 4; ++ot)
          acc[mt][ot] = __builtin_amdgcn_mfma_f32_16x16x32_bf16(af[mt], bf[ot], acc[mt][ot], 0, 0, 0);
    }
    __syncthreads();
  }

  #pragma unroll
  for (int ot = 0; ot < 4; ++ot) {
    int o = o0 + wc * 64 + ot * 16 + l15;
    if (o >= O) continue;
    float bi = biasF ? biasF[o] : 0.f;
    #pragma unroll
    for (int mt = 0; mt < MT; ++mt) {
      int nb = n0 + wr * (TM / 2) + mt * 16 + quad * 4;
      float vals[4];
      #pragma unroll
      for (int r = 0; r < 4; ++r) {
        float val = acc[mt][ot][r] + bi;
        if (act == 1)      val = fmaxf(val, 0.f);
        else if (act == 2) val = (val >= 0.f) ? val : 0.2f * val;
        vals[r] = val;
      }
      if (outF)
        *(float4*)&outF[(long)b * sOutF + (long)o * ldOutF + nb] = *(float4*)vals;
      if (outH) {
        unsigned short t[4];
        #pragma unroll
        for (int r = 0; r < 4; ++r) t[r] = f2bf(vals[r]);
        *(uint2*)&outH[(long)b * sOutH + (long)o * ldOutH + nb] = *(uint2*)&t[0];
      }
    }
  }
}

// ---------------------------------------------------------------------------
// Gram row-stats, split-M: seg processes m in [seg*1024, seg*1024+1024).
// Outputs per-seg online-softmax partials (max, sum) per n.
// grid (g, 32, 2): b fastest -> XCD = b%8. Dbuf LDS (32KB -> 4 blocks/CU).
// ---------------------------------------------------------------------------
__global__ __launch_bounds__(256)
void gram_lw(const unsigned short* __restrict__ xk, long sXk,
             float* __restrict__ pm, float* __restrict__ ps) {
  __shared__ unsigned short lK[2][64 * 128];
  int tid = threadIdx.x, wave = tid >> 6, lane = tid & 63;
  int quad = lane >> 4, l15 = lane & 15;
  int rowL4 = lane >> 4, s16 = lane & 15;
  int n0 = blockIdx.y * 64, b = blockIdx.x, seg = blockIdx.z;
  int mbase = seg * 1024;
  const unsigned short* Kp = xk + (long)b * sXk;
  short8 afr[4];
  {
    const unsigned short* arow = Kp + (long)(n0 + wave * 16 + l15) * 128;
    #pragma unroll
    for (int kf = 0; kf < 4; ++kf) afr[kf] = *(const short8*)(arow + kf * 32 + quad * 8);
  }
  float runm[4], runs[4];
  #pragma unroll
  for (int r = 0; r < 4; ++r) { runm[r] = -1e30f; runs[r] = 0.f; }

  auto stage = [&](int ch, int bf) {
    #pragma unroll
    for (int t = 0; t < 4; ++t) {
      int c = t * 4 + wave;
      int row = c * 4 + rowL4;
      int gseg = (s16 & 8) | ((s16 ^ (row & 7)) & 7);
      dma16(Kp + (long)(mbase + ch * 64 + row) * 128 + gseg * 8, &lK[bf][c * 512]);
    }
  };
  stage(0, 0);

  for (int ch = 0; ch < 16; ++ch) {
    __syncthreads();
    int bf = ch & 1;
    if (ch + 1 < 16) stage(ch + 1, bf ^ 1);
    f32x4 sv[4];
    #pragma unroll
    for (int mf = 0; mf < 4; ++mf) {
      f32x4 s = (f32x4){0.f, 0.f, 0.f, 0.f};
      #pragma unroll
      for (int kf = 0; kf < 4; ++kf) {
        int r = mf * 16 + l15, q = kf * 4 + quad;
        int sp = (q & 8) | ((q ^ (r & 7)) & 7);
        short8 bfr = *(const short8*)&lK[bf][r * 128 + sp * 8];
        s = __builtin_amdgcn_mfma_f32_16x16x32_bf16(afr[kf], bfr, s, 0, 0, 0);
      }
      sv[mf] = s;
    }
    #pragma unroll
    for (int r = 0; r < 4; ++r) {
      float e0 = sv[0][r], e1 = sv[1][r], e2 = sv[2][r], e3 = sv[3][r];
      float cm = fmaxf(fmaxf(e0, e1), fmaxf(e2, e3));
      float mn = fmaxf(runm[r], cm);
      runs[r] = runs[r] * __expf(runm[r] - mn) +
                (__expf(e0 - mn) + __expf(e1 - mn)) + (__expf(e2 - mn) + __expf(e3 - mn));
      runm[r] = mn;
    }
  }
  #pragma unroll
  for (int r = 0; r < 4; ++r) {
    float m = runm[r], s = runs[r];
    #pragma unroll
    for (int off = 1; off < 16; off <<= 1) {
      float mo = __shfl_xor(m, off), so = __shfl_xor(s, off);
      float mn = fmaxf(m, mo);
      s = s * __expf(m - mn) + so * __expf(mo - mn);
      m = mn;
    }
    if (l15 == 0) {
      int n = n0 + wave * 16 + quad * 4 + r;
      pm[((long)b * 2 + seg) * 2048 + n] = m;
      ps[((long)b * 2 + seg) * 2048 + n] = s;
    }
  }
}

// merge 2 online-softmax partials -> lw = mx + log(sum). grid (8, g), 256.
__global__ void lwred_k(const float* __restrict__ pm, const float* __restrict__ ps,
                        float* __restrict__ lw) {
  int n = blockIdx.x * 256 + threadIdx.x, b = blockIdx.y;
  float m0 = pm[((long)b * 2) * 2048 + n], m1 = pm[((long)b * 2 + 1) * 2048 + n];
  float s0 = ps[((long)b * 2) * 2048 + n], s1 = ps[((long)b * 2 + 1) * 2048 + n];
  float mx = fmaxf(m0, m1);
  float s = s0 * __expf(m0 - mx) + s1 * __expf(m1 - mx);
  lw[(long)b * 2048 + n] = mx + __logf(s);
}

// ---------------------------------------------------------------------------
// Fused PV, split-N: seg processes n in [seg*1024, seg*1024+1024).
// Single-buffered K/V (33KB LDS -> 4 blocks/CU; grid 1024 fully resident).
// Outputs fp32 PV partials pacc[b][seg][m][d] and colsum partials pc.
// grid (g, 32, 2): b fastest.
// ---------------------------------------------------------------------------
__global__ __launch_bounds__(256)
void pv_k(const unsigned short* __restrict__ xk, long sXk,
          const unsigned short* __restrict__ xv, long sXv,
          const float* __restrict__ lw,
          float* __restrict__ pacc, float* __restrict__ pc) {
  __shared__ unsigned short lK[64 * 128];
  __shared__ unsigned short lV[128 * 64];
  __shared__ float lwt[64];
  int tid = threadIdx.x, wave = tid >> 6, lane = tid & 63;
  int quad = lane >> 4, l15 = lane & 15;
  int rowL4 = lane >> 4, s16 = lane & 15;
  int rowL8 = lane >> 3, s8 = lane & 7;
  int m0 = blockIdx.y * 64, b = blockIdx.x, seg = blockIdx.z;
  int nbase = seg * 1024;
  const unsigned short* Kp = xk + (long)b * sXk;
  const unsigned short* Vp = xv + (long)b * sXv;
  short8 akr[4];
  {
    const unsigned short* arow = Kp + (long)(m0 + wave * 16 + l15) * 128;
    #pragma unroll
    for (int kf = 0; kf < 4; ++kf) akr[kf] = *(const short8*)(arow + kf * 32 + quad * 8);
  }
  f32x4 acc[8];
  #pragma unroll
  for (int dt = 0; dt < 8; ++dt) acc[dt] = (f32x4){0.f, 0.f, 0.f, 0.f};
  float runc = 0.f;

  for (int ch = 0; ch < 16; ++ch) {
    if (ch) __syncthreads();
    #pragma unroll
    for (int t = 0; t < 4; ++t) {
      int c = t * 4 + wave;
      int rowK = c * 4 + rowL4;
      int gsegK = (s16 & 8) | ((s16 ^ (rowK & 7)) & 7);
      dma16(Kp + (long)(nbase + ch * 64 + rowK) * 128 + gsegK * 8, &lK[c * 512]);
      int rowV = c * 8 + rowL8;
      int gsegV = s8 ^ (rowV & 7);
      dma16(Vp + (long)rowV * 2048 + nbase + ch * 64 + gsegV * 8, &lV[c * 512]);
    }
    if (tid < 64) lwt[tid] = lw[(long)b * 2048 + nbase + ch * 64 + tid];
    __syncthreads();
    // S_T: lane holds p[m=l15][n = local nf*16 + quad*4 + r], packed bf16
    unsigned pd0[4], pd1[4];
    #pragma unroll
    for (int nf = 0; nf < 4; ++nf) {
      f32x4 s = (f32x4){0.f, 0.f, 0.f, 0.f};
      #pragma unroll
      for (int kf = 0; kf < 4; ++kf) {
        int r = nf * 16 + l15, q = kf * 4 + quad;
        int sp = (q & 8) | ((q ^ (r & 7)) & 7);
        short8 kfr = *(const short8*)&lK[r * 128 + sp * 8];
        s = __builtin_amdgcn_mfma_f32_16x16x32_bf16(kfr, akr[kf], s, 0, 0, 0);
      }
      float4 lw4 = *(const float4*)&lwt[nf * 16 + quad * 4];
      float lwv[4] = {lw4.x, lw4.y, lw4.z, lw4.w};
      unsigned short t4[4];
      #pragma unroll
      for (int r = 0; r < 4; ++r) {
        float p = __expf(s[r] - lwv[r]);
        runc += p;
        t4[r] = f2bf(p);
      }
      pd0[nf] = (unsigned)t4[0] | ((unsigned)t4[1] << 16);
      pd1[nf] = (unsigned)t4[2] | ((unsigned)t4[3] << 16);
    }
    // PV: A-frag via in-register transpose (4 shfls per kc)
    #pragma unroll
    for (int kc = 0; kc < 2; ++kc) {
      unsigned d0 = (quad >= 2) ? pd0[2 * kc + 1] : pd0[2 * kc];
      unsigned d1 = (quad >= 2) ? pd1[2 * kc + 1] : pd1[2 * kc];
      int s0 = ((quad & 1) << 5) + l15;
      union { unsigned u[4]; short8 v; } pu;
      pu.u[0] = (unsigned)__shfl((int)d0, s0);
      pu.u[1] = (unsigned)__shfl((int)d1, s0);
      pu.u[2] = (unsigned)__shfl((int)d0, s0 + 16);
      pu.u[3] = (unsigned)__shfl((int)d1, s0 + 16);
      short8 pa = pu.v;
      #pragma unroll
      for (int dt = 0; dt < 8; ++dt) {
        int r = dt * 16 + l15;
        int spv = (kc * 4 + quad) ^ (r & 7);
        short8 vb = *(const short8*)&lV[r * 64 + spv * 8];
        acc[dt] = __builtin_amdgcn_mfma_f32_16x16x32_bf16(pa, vb, acc[dt], 0, 0, 0);
      }
    }
  }
  // colsum partial per m=l15 (reduce over quads)
  float s = runc;
  s += __shfl_xor(s, 16);
  s += __shfl_xor(s, 32);
  if (quad == 0)
    pc[((long)b * 2 + seg) * 2048 + m0 + wave * 16 + l15] = s;
  // PV partials
  float* pa = pacc + ((long)b * 2 + seg) * 262144;
  #pragma unroll
  for (int dt = 0; dt < 8; ++dt) {
    int d = dt * 16 + l15;
    #pragma unroll
    for (int r = 0; r < 4; ++r)
      pa[(long)(m0 + wave * 16 + quad * 4 + r) * 128 + d] = acc[dt][r];
  }
}

// combine PV partials: xrb = bf16(li - (P0+P1)/(1e-9+c0+c1)). grid (256, g).
__global__ __launch_bounds__(256)
void pvred_k(const float* __restrict__ pacc, const float* __restrict__ pc,
             const unsigned short* __restrict__ lib, long sLi, int ldLi,
             unsigned short* __restrict__ xrb, long sXr) {
  int i = blockIdx.x * 256 + threadIdx.x;
  int b = blockIdx.y;
  int m = i >> 5, d4 = (i & 31) * 4;
  float4 a0 = *(const float4*)&pacc[((long)b * 2 + 0) * 262144 + (long)m * 128 + d4];
  float4 a1 = *(const float4*)&pacc[((long)b * 2 + 1) * 262144 + (long)m * 128 + d4];
  float c = pc[((long)b * 2) * 2048 + m] + pc[((long)b * 2 + 1) * 2048 + m];
  float inv = 1.f / (1e-9f + c);
  uint2 lv = *(const uint2*)&lib[(long)b * sLi + (long)m * ldLi + d4];
  unsigned short lr[4];
  *(uint2*)lr = lv;
  unsigned short o[4];
  o[0] = f2bf(bf2f(lr[0]) - (a0.x + a1.x) * inv);
  o[1] = f2bf(bf2f(lr[1]) - (a0.y + a1.y) * inv);
  o[2] = f2bf(bf2f(lr[2]) - (a0.z + a1.z) * inv);
  o[3] = f2bf(bf2f(lr[3]) - (a0.w + a1.w) * inv);
  *(uint2*)&xrb[(long)b * sXr + (long)m * 128 + d4] = *(uint2*)&o[0];
}

// ---------------------------------------------------------------------------
__global__ void poolred_k(const float* __restrict__ pmax, const float* __restrict__ psum,
                          float* __restrict__ xmax, float* __restrict__ xavg) {
  int f = blockIdx.x * 256 + threadIdx.x, b = blockIdx.y;
  float mx = -1e30f, s = 0.f;
  #pragma unroll
  for (int t = 0; t < 16; ++t) {
    mx = fmaxf(mx, pmax[((long)b * 16 + t) * 1024 + f]);
    s += psum[((long)b * 16 + t) * 1024 + f];
  }
  xmax[(long)b * 1024 + f] = mx;
  xavg[(long)b * 1024 + f] = s * (1.f / 2048.f);
}

// pt[b][o] = sc1[o] * ( ws1[o][1024:2048].xmax + ws1[o][2048:3072].xavg )
__global__ __launch_bounds__(256)
void poolterm_k(const float* __restrict__ ws1, const float* __restrict__ xmax,
                const float* __restrict__ xavg,
                const float* __restrict__ bg, const float* __restrict__ bv,
                float* __restrict__ pt) {
  int o = blockIdx.x, b = blockIdx.y, tid = threadIdx.x;
  const float* w = ws1 + (long)o * 3072;
  float s = 0.f;
  #pragma unroll
  for (int it = 0; it < 4; ++it) {
    int c = tid + it * 256;
    s += w[1024 + c] * xmax[(long)b * 1024 + c] + w[2048 + c] * xavg[(long)b * 1024 + c];
  }
  #pragma unroll
  for (int off = 32; off; off >>= 1) s += __shfl_xor(s, off);
  __shared__ float rsm[4];
  if ((tid & 63) == 0) rsm[tid >> 6] = s;
  __syncthreads();
  if (tid == 0) {
    float sc = bg[o] * rsqrtf(bv[o] + BN_EPS);
    pt[(long)b * H1_ + o] = sc * (rsm[0] + rsm[1] + rsm[2] + rsm[3]);
  }
}

// ---------------------------------------------------------------------------
extern "C" void kernel_launch(void* const* d_in, const int* in_sizes, int n_in,
                              void* d_out, int out_size, void* d_ws, size_t ws_size,
                              hipStream_t stream) {
  const float* x      = (const float*)d_in[0];
  const float* w1     = (const float*)d_in[1];
  const float* w2     = (const float*)d_in[2];
  const float* bn1_g  = (const float*)d_in[3];
  const float* bn1_b  = (const float*)d_in[4];
  const float* bn1_m  = (const float*)d_in[5];
  const float* bn1_v  = (const float*)d_in[6];
  const float* bn2_g  = (const float*)d_in[7];
  const float* bn2_b  = (const float*)d_in[8];
  const float* bn2_m  = (const float*)d_in[9];
  const float* bn2_v  = (const float*)d_in[10];
  const float* sa_wqk = (const float*)d_in[11];
  const float* sa_wv  = (const float*)d_in[12];
  const float* sa_bv  = (const float*)d_in[13];
  const float* sa_wt  = (const float*)d_in[14];
  const float* sa_bt  = (const float*)d_in[15];
  const float* sa_g   = (const float*)d_in[16];
  const float* sa_b   = (const float*)d_in[17];
  const float* sa_m   = (const float*)d_in[18];
  const float* sa_v   = (const float*)d_in[19];
  const float* wf     = (const float*)d_in[20];
  const float* bnf_g  = (const float*)d_in[21];
  const float* bnf_b  = (const float*)d_in[22];
  const float* bnf_m  = (const float*)d_in[23];
  const float* bnf_v  = (const float*)d_in[24];
  const float* ws1    = (const float*)d_in[25];
  const float* bs1    = (const float*)d_in[26];
  const float* bns1_g = (const float*)d_in[27];
  const float* bns1_b = (const float*)d_in[28];
  const float* bns1_m = (const float*)d_in[29];
  const float* bns1_v = (const float*)d_in[30];
  const float* ws2    = (const float*)d_in[31];
  const float* bs2    = (const float*)d_in[32];
  const float* bns2_g = (const float*)d_in[33];
  const float* bns2_b = (const float*)d_in[34];
  const float* bns2_m = (const float*)d_in[35];
  const float* bns2_v = (const float*)d_in[36];
  float* out = (float*)d_out;

  float* ws = (float*)d_ws;
  size_t off = 0;
  auto alloc  = [&](size_t n) { float* p = ws + off; off += (n + 63) & ~(size_t)63; return p; };
  auto allocH = [&](size_t n) { return (unsigned short*)alloc((n + 1) / 2); };

  unsigned short* w2b  = allocH(128 * 128);
  unsigned short* wqkb = allocH(4 * 128 * 128);
  unsigned short* wvb  = allocH(4 * 128 * 128);
  unsigned short* wtb  = allocH(4 * 128 * 128);
  unsigned short* wfb  = allocH((size_t)F_ * 512);
  unsigned short* ws1b = allocH((size_t)H1_ * 1024);
  unsigned short* ws2b = allocH((size_t)128 * 512);
  float* bias_w2 = alloc(128);
  float* bias_v  = alloc(512);
  float* bias_t  = alloc(512);
  float* bias_f  = alloc(1024);
  float* bias_s1 = alloc(512);
  float* bias_s2 = alloc(128);
  float* lwB  = alloc((size_t)16 * 2048);
  float* pmax = alloc((size_t)16 * 16 * 1024);
  float* psum = alloc((size_t)16 * 16 * 1024);
  float* xmaxB = alloc((size_t)16 * 1024);
  float* xavgB = alloc((size_t)16 * 1024);
  float* ptB   = alloc((size_t)16 * 512);
  size_t fixedOff = off;

  // per-batch (floats): h1b 131072 + featsb 524288 + fusedb 1048576 +
  //   xkb/xvb/xrb 3*131072 + pacc 524288 + pm/ps/pc 3*4096
  const size_t perB = 131072 + 524288 + 1048576 + 131072 + 131072 + 131072 +
                      524288 + 12288;
  size_t wsFloats = ws_size / 4;
  int Gb = 1;
  for (int c : {16, 8, 4, 2, 1}) {
    if (fixedOff + (size_t)c * perB + 4096 <= wsFloats) { Gb = c; break; }
  }

  unsigned short* h1b    = allocH((size_t)Gb * 262144);
  unsigned short* featsb = allocH((size_t)Gb * 1048576);   // hs1b aliases
  unsigned short* fusedb = allocH((size_t)Gb * 2097152);
  unsigned short* xkb    = allocH((size_t)Gb * 262144);
  unsigned short* xvb    = allocH((size_t)Gb * 262144);
  unsigned short* xrb    = allocH((size_t)Gb * 262144);    // h0b aliases
  float* paccB = alloc((size_t)Gb * 2 * 262144);
  float* pmB   = alloc((size_t)Gb * 2 * 2048);
  float* psB   = alloc((size_t)Gb * 2 * 2048);
  float* pcB   = alloc((size_t)Gb * 2 * 2048);
  unsigned short* h0b  = xrb;
  unsigned short* hs1b = featsb;

  foldw_k<<<64, 256, 0, stream>>>(w2, 128, nullptr, bn2_g, bn2_b, bn2_m, bn2_v,
                                  w2b, bias_w2, 128, 128, 128);
  for (int i = 0; i < 4; ++i) {
    foldw_k<<<64, 256, 0, stream>>>(sa_wqk + (size_t)i * 16384, 128, nullptr,
                                    nullptr, nullptr, nullptr, nullptr,
                                    wqkb + (size_t)i * 16384, nullptr, 128, 128, 128);
    foldw_k<<<64, 256, 0, stream>>>(sa_wv + (size_t)i * 16384, 128, sa_bv + i * 128,
                                    nullptr, nullptr, nullptr, nullptr,
                                    wvb + (size_t)i * 16384, bias_v + i * 128, 128, 128, 128);
    foldw_k<<<64, 256, 0, stream>>>(sa_wt + (size_t)i * 16384, 128, sa_bt + i * 128,
                                    sa_g + i * 128, sa_b + i * 128, sa_m + i * 128, sa_v + i * 128,
                                    wtb + (size_t)i * 16384, bias_t + i * 128, 128, 128, 128);
  }
  foldw_k<<<2048, 256, 0, stream>>>(wf, 512, nullptr, bnf_g, bnf_b, bnf_m, bnf_v,
                                    wfb, bias_f, 1024, 1024, 512);
  foldw_k<<<2048, 256, 0, stream>>>(ws1, 3072, bs1, bns1_g, bns1_b, bns1_m, bns1_v,
                                    ws1b, bias_s1, 512, 512, 1024);
  foldw_k<<<256, 256, 0, stream>>>(ws2, 512, bs2, bns2_g, bns2_b, bns2_m, bns2_v,
                                   ws2b, bias_s2, 50, 128, 512);

  const long sAct = 262144, sFeat = 1048576, sFus = 2097152;
  for (int b0 = 0; b0 < B_; b0 += Gb) {
    int g = Gb;
    conv1_k<<<dim3(N_, g), 128, 0, stream>>>(x + (long)b0 * 3 * N_, w1,
                                             bn1_g, bn1_b, bn1_m, bn1_v, h0b);
    // conv2+bn2+relu -> h1b bf16
    gemm_tok<64><<<dim3(32, 1, g), 256, 0, stream>>>(
        w2b, 128, h0b, sAct, 128, bias_w2, nullptr, 0, nullptr, 0, 0,
        h1b, sAct, 128, nullptr, nullptr, 128, 1, 0);

    for (int i = 0; i < 4; ++i) {
      const unsigned short* lib = (i == 0) ? h1b : featsb + (size_t)(i - 1) * 128;
      int ldLi = (i == 0) ? 128 : 512;
      long sLi = (i == 0) ? sAct : sFeat;
      // xk (bf16 token)
      gemm_tok<64><<<dim3(32, 1, g), 256, 0, stream>>>(
          wqkb + (size_t)i * 16384, 128, lib, sLi, ldLi, nullptr, nullptr, 0,
          nullptr, 0, 0, xkb, sAct, 128, nullptr, nullptr, 128, 0, 0);
      // xv (bf16 channel, +bv)
      gemm_chan<64><<<dim3(32, 1, g), 256, 0, stream>>>(
          wvb + (size_t)i * 16384, 128, lib, sLi, ldLi, bias_v + i * 128,
          nullptr, 0, 0, xvb, sAct, 2048, 128, 128, 0);
      gram_lw<<<dim3(g, 32, 2), 256, 0, stream>>>(xkb, sAct, pmB, psB);
      lwred_k<<<dim3(8, g), 256, 0, stream>>>(pmB, psB, lwB);
      pv_k<<<dim3(g, 32, 2), 256, 0, stream>>>(xkb, sAct, xvb, sAct, lwB, paccB, pcB);
      pvred_k<<<dim3(256, g), 256, 0, stream>>>(paccB, pcB, lib, sLi, ldLi, xrb, sAct);
      // feats_i = li + relu(wt' @ (li - xr) + bt')   (res = bf16 li)
      gemm_tok<64><<<dim3(32, 1, g), 256, 0, stream>>>(
          wtb + (size_t)i * 16384, 128, xrb, sAct, 128, bias_t + i * 128, nullptr, 0,
          lib, sLi, ldLi,
          featsb + (size_t)i * 128, sFeat, 512, nullptr, nullptr, 128, 1, 16);
    }

    // fused = leaky(wf' @ feats + bf') -> bf16 + pool partials
    gemm_tok<128><<<dim3(16, 8, g), 256, 0, stream>>>(
        wfb, 512, featsb, sFeat, 512, bias_f, nullptr, 0, nullptr, 0, 0,
        fusedb, sFus, 1024, pmax, psum, 512, 2, 32);
    poolred_k<<<dim3(4, g), 256, 0, stream>>>(pmax, psum, xmaxB, xavgB);
    poolterm_k<<<dim3(512, g), 256, 0, stream>>>(ws1, xmaxB, xavgB, bns1_g, bns1_v, ptB);
    // hs1 = relu(ws1' @ fused + bs1' + pt) -> bf16
    gemm_tok<128><<<dim3(16, 4, g), 256, 0, stream>>>(
        ws1b, 1024, fusedb, sFus, 1024, bias_s1, ptB, 512, nullptr, 0, 0,
        hs1b, sFeat, 512, nullptr, nullptr, 1024, 1, 0);
    // out = relu(ws2' @ hs1 + bs2') -> fp32 channel-major
    gemm_chan<64><<<dim3(32, 1, g), 256, 0, stream>>>(
        ws2b, 512, hs1b, sFeat, 512, bias_s2,
        out + (long)b0 * OUT_ * N_, (long)OUT_ * N_, 2048, nullptr, 0, 0,
        512, 50, 1);
  }
}

// Round 13
// 761.412 us; speedup vs baseline: 1.4528x; 1.0323x over previous
//
#include <hip/hip_runtime.h>
#include <cstdint>
#include <cstddef>

#define B_   16
#define N_   2048
#define D_   128
#define F_   1024
#define H1_  512
#define OUT_ 50

static constexpr float BN_EPS = 1e-5f;

typedef __attribute__((ext_vector_type(8))) short short8;
typedef __attribute__((ext_vector_type(4))) float f32x4;

__device__ inline unsigned short f2bf(float f) {
  union { float f; unsigned u; } v; v.f = f;
  unsigned r = v.u + 0x7fff + ((v.u >> 16) & 1);
  return (unsigned short)(r >> 16);
}
__device__ inline float bf2f(unsigned short h) {
  union { unsigned u; float f; } v; v.u = ((unsigned)h) << 16; return v.f;
}

// async global->LDS, 16B per lane; LDS dest = wave-uniform base + lane*16
__device__ inline void dma16(const unsigned short* g, unsigned short* l) {
  __builtin_amdgcn_global_load_lds(
      (const __attribute__((address_space(1))) unsigned int*)g,
      (__attribute__((address_space(3))) unsigned int*)l, 16, 0, 0);
}

// ---------------------------------------------------------------------------
// Fold BN (+bias) into bf16 weights + fp32 bias.
// ---------------------------------------------------------------------------
__global__ void foldw_k(const float* __restrict__ W, int ldW,
                        const float* __restrict__ bias,
                        const float* __restrict__ g, const float* __restrict__ bb,
                        const float* __restrict__ m, const float* __restrict__ v,
                        unsigned short* __restrict__ Wb, float* __restrict__ biasF,
                        int O, int Opad, int K) {
  long i = (long)blockIdx.x * 256 + threadIdx.x;
  if (i >= (long)Opad * K) return;
  int o = (int)(i / K), k = (int)(i % K);
  float sc = 1.f, sh = 0.f;
  if (o < O && g) { sc = g[o] * rsqrtf(v[o] + BN_EPS); sh = bb[o] - m[o] * sc; }
  float w = (o < O) ? W[(long)o * ldW + k] * sc : 0.f;
  Wb[i] = f2bf(w);
  if (k == 0 && biasF) {
    float bf = 0.f;
    if (o < O) bf = (bias ? bias[o] : 0.f) * sc + sh;
    biasF[o] = bf;
  }
}

// ---------------------------------------------------------------------------
// conv1 (3->128) + bn + relu -> bf16 token-major. grid (N, g), block 128
// ---------------------------------------------------------------------------
__global__ void conv1_k(const float* __restrict__ x, const float* __restrict__ w1,
                        const float* __restrict__ g, const float* __restrict__ bb,
                        const float* __restrict__ m, const float* __restrict__ v,
                        unsigned short* __restrict__ h0b) {
  int o = threadIdx.x, n = blockIdx.x, b = blockIdx.y;
  const float* xb = x + (long)b * 3 * N_;
  float val = w1[o * 3 + 0] * xb[n] + w1[o * 3 + 1] * xb[N_ + n] + w1[o * 3 + 2] * xb[2 * N_ + n];
  float sc = g[o] * rsqrtf(v[o] + BN_EPS);
  val = val * sc + (bb[o] - m[o] * sc);
  h0b[((long)b * N_ + n) * D_ + o] = f2bf(fmaxf(val, 0.f));
}

// ---------------------------------------------------------------------------
// Token-output MFMA GEMM (swapped operands): out[n][o] bf16, O mult of 128.
// Tile TM x 128, BK=64, block 256 (2x2 waves). DMA staging + XOR swizzle.
// Epilogue: LDS repack -> 256B-row vector stores.
// flags: 16 add bf16 res after act | 32 pool partials
// ---------------------------------------------------------------------------
template <int TM>
__global__ __launch_bounds__(256, 4)
void gemm_tok(const unsigned short* __restrict__ Wb, int ldW,
              const unsigned short* __restrict__ A, long sA, int ldA,
              const float* __restrict__ biasF,
              const float* __restrict__ perBO, int ldPBO,
              const unsigned short* __restrict__ resH, long sRes, int ldRes,
              unsigned short* __restrict__ outH, long sOutH, int ldOutH,
              float* __restrict__ pmax, float* __restrict__ psum,
              int K, int act, int flags) {
  constexpr int MT = TM / 32;
  __shared__ unsigned short lAB[TM * 64 + 128 * 64];
  __shared__ float lpm[4][64], lps[4][64];
  unsigned short* lA = lAB;
  unsigned short* lB = lAB + TM * 64;
  unsigned short* lS = lAB;                 // repack tile TM x 128 (aliases)
  int tid = threadIdx.x;
  int n0 = blockIdx.x * TM, o0 = blockIdx.y * 128, b = blockIdx.z;
  int wave = tid >> 6, lane = tid & 63;
  int wr = wave >> 1, wc = wave & 1;
  int quad = lane >> 4, l15 = lane & 15;
  int rowL = lane >> 3;
  int kseg = (lane & 7) ^ rowL;
  const unsigned short* Ab = A + (long)b * sA + (long)n0 * ldA;
  const unsigned short* Wp = Wb + (long)o0 * ldW;

  f32x4 acc[MT][4];
  #pragma unroll
  for (int i = 0; i < MT; ++i)
    #pragma unroll
    for (int j = 0; j < 4; ++j) acc[i][j] = (f32x4){0.f, 0.f, 0.f, 0.f};

  for (int kc = 0; kc < K; kc += 64) {
    #pragma unroll
    for (int t = 0; t < 4; ++t) {
      int chunk = t * 4 + wave;
      dma16(Wp + (long)(chunk * 8 + rowL) * ldW + kc + kseg * 8, &lB[chunk * 512]);
      if (chunk < TM / 8)
        dma16(Ab + (long)(chunk * 8 + rowL) * ldA + kc + kseg * 8, &lA[chunk * 512]);
    }
    __syncthreads();
    #pragma unroll
    for (int kk = 0; kk < 2; ++kk) {
      short8 af[MT], bf[4];
      #pragma unroll
      for (int mt = 0; mt < MT; ++mt) {
        int r = wr * (TM / 2) + mt * 16 + l15;
        af[mt] = *(const short8*)&lA[r * 64 + (((kk * 4 + quad) ^ (l15 & 7)) * 8)];
      }
      #pragma unroll
      for (int ot = 0; ot < 4; ++ot) {
        int r = wc * 64 + ot * 16 + l15;
        bf[ot] = *(const short8*)&lB[r * 64 + (((kk * 4 + quad) ^ (l15 & 7)) * 8)];
      }
      #pragma unroll
      for (int mt = 0; mt < MT; ++mt)
        #pragma unroll
        for (int ot = 0; ot < 4; ++ot)
          acc[mt][ot] = __builtin_amdgcn_mfma_f32_16x16x32_bf16(bf[ot], af[mt], acc[mt][ot], 0, 0, 0);
    }
    __syncthreads();
  }

  bool doPool = (flags & 32) != 0;
  #pragma unroll
  for (int ot = 0; ot < 4; ++ot) {
    int obL = wc * 64 + ot * 16 + quad * 4;
    int ob = o0 + obL;
    float bi[4] = {0.f, 0.f, 0.f, 0.f};
    if (biasF) { float4 t = *(const float4*)&biasF[ob]; bi[0] = t.x; bi[1] = t.y; bi[2] = t.z; bi[3] = t.w; }
    if (perBO) {
      float4 t = *(const float4*)&perBO[(long)b * ldPBO + ob];
      bi[0] += t.x; bi[1] += t.y; bi[2] += t.z; bi[3] += t.w;
    }
    float pm4[4], ps4[4];
    #pragma unroll
    for (int r = 0; r < 4; ++r) { pm4[r] = -1e30f; ps4[r] = 0.f; }
    int g = obL >> 3, go = obL & 7;
    #pragma unroll
    for (int mt = 0; mt < MT; ++mt) {
      int nL = wr * (TM / 2) + mt * 16 + l15;
      float vals[4];
      #pragma unroll
      for (int r = 0; r < 4; ++r) {
        float val = acc[mt][ot][r] + bi[r];
        if (act == 1)      val = fmaxf(val, 0.f);
        else if (act == 2) val = (val >= 0.f) ? val : 0.2f * val;
        vals[r] = val;
      }
      if (flags & 16) {
        uint2 rv = *(const uint2*)&resH[(long)b * sRes + (long)(n0 + nL) * ldRes + ob];
        unsigned short rr[4];
        *(uint2*)rr = rv;
        #pragma unroll
        for (int r = 0; r < 4; ++r) vals[r] += bf2f(rr[r]);
      }
      unsigned short t4[4];
      #pragma unroll
      for (int r = 0; r < 4; ++r) {
        t4[r] = f2bf(vals[r]);
        if (doPool) { pm4[r] = fmaxf(pm4[r], vals[r]); ps4[r] += vals[r]; }
      }
      int gp = (g & 8) | ((g ^ (nL & 7)) & 7);
      *(uint2*)&lS[nL * 128 + gp * 8 + go] = *(uint2*)&t4[0];
    }
    if (doPool) {
      #pragma unroll
      for (int r = 0; r < 4; ++r) {
        float m = pm4[r], s = ps4[r];
        m = fmaxf(m, __shfl_xor(m, 1)); s += __shfl_xor(s, 1);
        m = fmaxf(m, __shfl_xor(m, 2)); s += __shfl_xor(s, 2);
        m = fmaxf(m, __shfl_xor(m, 4)); s += __shfl_xor(s, 4);
        m = fmaxf(m, __shfl_xor(m, 8)); s += __shfl_xor(s, 8);
        if (l15 == 0) { lpm[wave][ot * 16 + quad * 4 + r] = m; lps[wave][ot * 16 + quad * 4 + r] = s; }
      }
    }
  }
  __syncthreads();
  {
    int r0 = tid >> 4, s = tid & 15;
    #pragma unroll
    for (int it = 0; it < TM / 16; ++it) {
      int row = it * 16 + r0;
      int sp = (s & 8) | ((s ^ (row & 7)) & 7);
      short8 v = *(const short8*)&lS[row * 128 + sp * 8];
      *(short8*)&outH[(long)b * sOutH + (long)(n0 + row) * ldOutH + o0 + s * 8] = v;
    }
  }
  if (doPool && tid < 128) {
    int wcx = tid >> 6, ol = tid & 63;
    float m = fmaxf(lpm[wcx][ol], lpm[wcx + 2][ol]);
    float s = lps[wcx][ol] + lps[wcx + 2][ol];
    int o = o0 + wcx * 64 + ol;
    pmax[((long)b * 16 + blockIdx.x) * 1024 + o] = m;
    psum[((long)b * 16 + blockIdx.x) * 1024 + o] = s;
  }
}

// ---------------------------------------------------------------------------
// Channel-output MFMA GEMM (unswapped): out[o][n] fp32 or bf16; O guarded.
// ---------------------------------------------------------------------------
template <int TM>
__global__ __launch_bounds__(256, 4)
void gemm_chan(const unsigned short* __restrict__ Wb, int ldW,
               const unsigned short* __restrict__ A, long sA, int ldA,
               const float* __restrict__ biasF,
               float* __restrict__ outF, long sOutF, int ldOutF,
               unsigned short* __restrict__ outH, long sOutH, int ldOutH,
               int K, int O, int act) {
  constexpr int MT = TM / 32;
  __shared__ unsigned short lA[TM * 64];
  __shared__ unsigned short lB[128 * 64];
  int tid = threadIdx.x;
  int n0 = blockIdx.x * TM, o0 = blockIdx.y * 128, b = blockIdx.z;
  int wave = tid >> 6, lane = tid & 63;
  int wr = wave >> 1, wc = wave & 1;
  int quad = lane >> 4, l15 = lane & 15;
  int rowL = lane >> 3;
  int kseg = (lane & 7) ^ rowL;
  const unsigned short* Ab = A + (long)b * sA + (long)n0 * ldA;
  const unsigned short* Wp = Wb + (long)o0 * ldW;

  f32x4 acc[MT][4];
  #pragma unroll
  for (int i = 0; i < MT; ++i)
    #pragma unroll
    for (int j = 0; j < 4; ++j) acc[i][j] = (f32x4){0.f, 0.f, 0.f, 0.f};

  for (int kc = 0; kc < K; kc += 64) {
    #pragma unroll
    for (int t = 0; t < 4; ++t) {
      int chunk = t * 4 + wave;
      dma16(Wp + (long)(chunk * 8 + rowL) * ldW + kc + kseg * 8, &lB[chunk * 512]);
      if (chunk < TM / 8)
        dma16(Ab + (long)(chunk * 8 + rowL) * ldA + kc + kseg * 8, &lA[chunk * 512]);
    }
    __syncthreads();
    #pragma unroll
    for (int kk = 0; kk < 2; ++kk) {
      short8 af[MT], bf[4];
      #pragma unroll
      for (int mt = 0; mt < MT; ++mt) {
        int r = wr * (TM / 2) + mt * 16 + l15;
        af[mt] = *(const short8*)&lA[r * 64 + (((kk * 4 + quad) ^ (l15 & 7)) * 8)];
      }
      #pragma unroll
      for (int ot = 0; ot < 4; ++ot) {
        int r = wc * 64 + ot * 16 + l15;
        bf[ot] = *(const short8*)&lB[r * 64 + (((kk * 4 + quad) ^ (l15 & 7)) * 8)];
      }
      #pragma unroll
      for (int mt = 0; mt < MT; ++mt)
        #pragma unroll
        for (int ot = 0; ot < 4; ++ot)
          acc[mt][ot] = __builtin_amdgcn_mfma_f32_16x16x32_bf16(af[mt], bf[ot], acc[mt][ot], 0, 0, 0);
    }
    __syncthreads();
  }

  #pragma unroll
  for (int ot = 0; ot < 4; ++ot) {
    int o = o0 + wc * 64 + ot * 16 + l15;
    if (o >= O) continue;
    float bi = biasF ? biasF[o] : 0.f;
    #pragma unroll
    for (int mt = 0; mt < MT; ++mt) {
      int nb = n0 + wr * (TM / 2) + mt * 16 + quad * 4;
      float vals[4];
      #pragma unroll
      for (int r = 0; r < 4; ++r) {
        float val = acc[mt][ot][r] + bi;
        if (act == 1)      val = fmaxf(val, 0.f);
        else if (act == 2) val = (val >= 0.f) ? val : 0.2f * val;
        vals[r] = val;
      }
      if (outF)
        *(float4*)&outF[(long)b * sOutF + (long)o * ldOutF + nb] = *(float4*)vals;
      if (outH) {
        unsigned short t[4];
        #pragma unroll
        for (int r = 0; r < 4; ++r) t[r] = f2bf(vals[r]);
        *(uint2*)&outH[(long)b * sOutH + (long)o * ldOutH + nb] = *(uint2*)&t[0];
      }
    }
  }
}

// ---------------------------------------------------------------------------
// Gram row-stats, split-M, 2 n-groups/wave (each lK read feeds 2 MFMAs).
// Block n-tile 128. seg: m in [seg*1024, seg*1024+1024).
// grid (g, 16, 2): b fastest -> XCD = b%8. Dbuf LDS, 1 barrier/chunk.
// ---------------------------------------------------------------------------
__global__ __launch_bounds__(256)
void gram_lw(const unsigned short* __restrict__ xk, long sXk,
             float* __restrict__ pm, float* __restrict__ ps) {
  __shared__ unsigned short lK[2][64 * 128];
  int tid = threadIdx.x, wave = tid >> 6, lane = tid & 63;
  int quad = lane >> 4, l15 = lane & 15;
  int rowL4 = lane >> 4, s16 = lane & 15;
  int n0 = blockIdx.y * 128, b = blockIdx.x, seg = blockIdx.z;
  int mbase = seg * 1024;
  const unsigned short* Kp = xk + (long)b * sXk;
  short8 afr[2][4];
  #pragma unroll
  for (int g2 = 0; g2 < 2; ++g2) {
    const unsigned short* arow = Kp + (long)(n0 + g2 * 64 + wave * 16 + l15) * 128;
    #pragma unroll
    for (int kf = 0; kf < 4; ++kf) afr[g2][kf] = *(const short8*)(arow + kf * 32 + quad * 8);
  }
  float runm[2][4], runs[2][4];
  #pragma unroll
  for (int g2 = 0; g2 < 2; ++g2)
    #pragma unroll
    for (int r = 0; r < 4; ++r) { runm[g2][r] = -1e30f; runs[g2][r] = 0.f; }

  auto stage = [&](int ch, int bf) {
    #pragma unroll
    for (int t = 0; t < 4; ++t) {
      int c = t * 4 + wave;
      int row = c * 4 + rowL4;
      int gseg = (s16 & 8) | ((s16 ^ (row & 7)) & 7);
      dma16(Kp + (long)(mbase + ch * 64 + row) * 128 + gseg * 8, &lK[bf][c * 512]);
    }
  };
  stage(0, 0);

  for (int ch = 0; ch < 16; ++ch) {
    __syncthreads();
    int bf = ch & 1;
    if (ch + 1 < 16) stage(ch + 1, bf ^ 1);
    f32x4 sv[2][4];
    #pragma unroll
    for (int mf = 0; mf < 4; ++mf) {
      f32x4 sa = (f32x4){0.f, 0.f, 0.f, 0.f};
      f32x4 sb = (f32x4){0.f, 0.f, 0.f, 0.f};
      #pragma unroll
      for (int kf = 0; kf < 4; ++kf) {
        int r = mf * 16 + l15, q = kf * 4 + quad;
        int sp = (q & 8) | ((q ^ (r & 7)) & 7);
        short8 bfr = *(const short8*)&lK[bf][r * 128 + sp * 8];
        sa = __builtin_amdgcn_mfma_f32_16x16x32_bf16(afr[0][kf], bfr, sa, 0, 0, 0);
        sb = __builtin_amdgcn_mfma_f32_16x16x32_bf16(afr[1][kf], bfr, sb, 0, 0, 0);
      }
      sv[0][mf] = sa; sv[1][mf] = sb;
    }
    #pragma unroll
    for (int g2 = 0; g2 < 2; ++g2)
      #pragma unroll
      for (int r = 0; r < 4; ++r) {
        float e0 = sv[g2][0][r], e1 = sv[g2][1][r], e2 = sv[g2][2][r], e3 = sv[g2][3][r];
        float cm = fmaxf(fmaxf(e0, e1), fmaxf(e2, e3));
        float mn = fmaxf(runm[g2][r], cm);
        runs[g2][r] = runs[g2][r] * __expf(runm[g2][r] - mn) +
                      (__expf(e0 - mn) + __expf(e1 - mn)) + (__expf(e2 - mn) + __expf(e3 - mn));
        runm[g2][r] = mn;
      }
  }
  #pragma unroll
  for (int g2 = 0; g2 < 2; ++g2)
    #pragma unroll
    for (int r = 0; r < 4; ++r) {
      float m = runm[g2][r], s = runs[g2][r];
      #pragma unroll
      for (int off = 1; off < 16; off <<= 1) {
        float mo = __shfl_xor(m, off), so = __shfl_xor(s, off);
        float mn = fmaxf(m, mo);
        s = s * __expf(m - mn) + so * __expf(mo - mn);
        m = mn;
      }
      if (l15 == 0) {
        int n = n0 + g2 * 64 + wave * 16 + quad * 4 + r;
        pm[((long)b * 2 + seg) * 2048 + n] = m;
        ps[((long)b * 2 + seg) * 2048 + n] = s;
      }
    }
}

// merge 2 online-softmax partials -> lw = mx + log(sum). grid (8, g), 256.
__global__ void lwred_k(const float* __restrict__ pm, const float* __restrict__ ps,
                        float* __restrict__ lw) {
  int n = blockIdx.x * 256 + threadIdx.x, b = blockIdx.y;
  float m0 = pm[((long)b * 2) * 2048 + n], m1 = pm[((long)b * 2 + 1) * 2048 + n];
  float s0 = ps[((long)b * 2) * 2048 + n], s1 = ps[((long)b * 2 + 1) * 2048 + n];
  float mx = fmaxf(m0, m1);
  float s = s0 * __expf(m0 - mx) + s1 * __expf(m1 - mx);
  lw[(long)b * 2048 + n] = mx + __logf(s);
}

// ---------------------------------------------------------------------------
// Fused PV, split-N, 2 m-groups/wave (each lK/lV read feeds 2 MFMAs).
// Block m-tile 128. seg: n in [seg*1024, seg*1024+1024). Single-buffered.
// Outputs fp32 PV partials pacc[b][seg][m][d] + colsum partials pc.
// grid (g, 16, 2): b fastest.
// ---------------------------------------------------------------------------
__global__ __launch_bounds__(256)
void pv_k(const unsigned short* __restrict__ xk, long sXk,
          const unsigned short* __restrict__ xv, long sXv,
          const float* __restrict__ lw,
          float* __restrict__ pacc, float* __restrict__ pc) {
  __shared__ unsigned short lK[64 * 128];
  __shared__ unsigned short lV[128 * 64];
  __shared__ float lwt[64];
  int tid = threadIdx.x, wave = tid >> 6, lane = tid & 63;
  int quad = lane >> 4, l15 = lane & 15;
  int rowL4 = lane >> 4, s16 = lane & 15;
  int rowL8 = lane >> 3, s8 = lane & 7;
  int m0 = blockIdx.y * 128, b = blockIdx.x, seg = blockIdx.z;
  int nbase = seg * 1024;
  const unsigned short* Kp = xk + (long)b * sXk;
  const unsigned short* Vp = xv + (long)b * sXv;
  short8 akr[2][4];
  #pragma unroll
  for (int g2 = 0; g2 < 2; ++g2) {
    const unsigned short* arow = Kp + (long)(m0 + g2 * 64 + wave * 16 + l15) * 128;
    #pragma unroll
    for (int kf = 0; kf < 4; ++kf) akr[g2][kf] = *(const short8*)(arow + kf * 32 + quad * 8);
  }
  f32x4 acc[2][8];
  #pragma unroll
  for (int g2 = 0; g2 < 2; ++g2)
    #pragma unroll
    for (int dt = 0; dt < 8; ++dt) acc[g2][dt] = (f32x4){0.f, 0.f, 0.f, 0.f};
  float runc[2] = {0.f, 0.f};

  for (int ch = 0; ch < 16; ++ch) {
    if (ch) __syncthreads();
    #pragma unroll
    for (int t = 0; t < 4; ++t) {
      int c = t * 4 + wave;
      int rowK = c * 4 + rowL4;
      int gsegK = (s16 & 8) | ((s16 ^ (rowK & 7)) & 7);
      dma16(Kp + (long)(nbase + ch * 64 + rowK) * 128 + gsegK * 8, &lK[c * 512]);
      int rowV = c * 8 + rowL8;
      int gsegV = s8 ^ (rowV & 7);
      dma16(Vp + (long)rowV * 2048 + nbase + ch * 64 + gsegV * 8, &lV[c * 512]);
    }
    if (tid < 64) lwt[tid] = lw[(long)b * 2048 + nbase + ch * 64 + tid];
    __syncthreads();
    // S_T per m-group: lane holds p[m][n = nf*16 + quad*4 + r], packed bf16
    unsigned pd0[2][4], pd1[2][4];
    #pragma unroll
    for (int nf = 0; nf < 4; ++nf) {
      f32x4 sa = (f32x4){0.f, 0.f, 0.f, 0.f};
      f32x4 sb = (f32x4){0.f, 0.f, 0.f, 0.f};
      #pragma unroll
      for (int kf = 0; kf < 4; ++kf) {
        int r = nf * 16 + l15, q = kf * 4 + quad;
        int sp = (q & 8) | ((q ^ (r & 7)) & 7);
        short8 kfr = *(const short8*)&lK[r * 128 + sp * 8];
        sa = __builtin_amdgcn_mfma_f32_16x16x32_bf16(kfr, akr[0][kf], sa, 0, 0, 0);
        sb = __builtin_amdgcn_mfma_f32_16x16x32_bf16(kfr, akr[1][kf], sb, 0, 0, 0);
      }
      float4 lw4 = *(const float4*)&lwt[nf * 16 + quad * 4];
      float lwv[4] = {lw4.x, lw4.y, lw4.z, lw4.w};
      unsigned short ta[4], tb[4];
      #pragma unroll
      for (int r = 0; r < 4; ++r) {
        float p0 = __expf(sa[r] - lwv[r]);
        float p1 = __expf(sb[r] - lwv[r]);
        runc[0] += p0; runc[1] += p1;
        ta[r] = f2bf(p0); tb[r] = f2bf(p1);
      }
      pd0[0][nf] = (unsigned)ta[0] | ((unsigned)ta[1] << 16);
      pd1[0][nf] = (unsigned)ta[2] | ((unsigned)ta[3] << 16);
      pd0[1][nf] = (unsigned)tb[0] | ((unsigned)tb[1] << 16);
      pd1[1][nf] = (unsigned)tb[2] | ((unsigned)tb[3] << 16);
    }
    // PV: per kc build both pa via shfl transpose; each vb read feeds 2 MFMAs
    #pragma unroll
    for (int kc = 0; kc < 2; ++kc) {
      short8 paf[2];
      #pragma unroll
      for (int g2 = 0; g2 < 2; ++g2) {
        unsigned d0 = (quad >= 2) ? pd0[g2][2 * kc + 1] : pd0[g2][2 * kc];
        unsigned d1 = (quad >= 2) ? pd1[g2][2 * kc + 1] : pd1[g2][2 * kc];
        int s0 = ((quad & 1) << 5) + l15;
        union { unsigned u[4]; short8 v; } pu;
        pu.u[0] = (unsigned)__shfl((int)d0, s0);
        pu.u[1] = (unsigned)__shfl((int)d1, s0);
        pu.u[2] = (unsigned)__shfl((int)d0, s0 + 16);
        pu.u[3] = (unsigned)__shfl((int)d1, s0 + 16);
        paf[g2] = pu.v;
      }
      #pragma unroll
      for (int dt = 0; dt < 8; ++dt) {
        int r = dt * 16 + l15;
        int spv = (kc * 4 + quad) ^ (r & 7);
        short8 vb = *(const short8*)&lV[r * 64 + spv * 8];
        acc[0][dt] = __builtin_amdgcn_mfma_f32_16x16x32_bf16(paf[0], vb, acc[0][dt], 0, 0, 0);
        acc[1][dt] = __builtin_amdgcn_mfma_f32_16x16x32_bf16(paf[1], vb, acc[1][dt], 0, 0, 0);
      }
    }
  }
  // colsum partials per m (m = m0 + g2*64 + wave*16 + l15), reduce over quads
  #pragma unroll
  for (int g2 = 0; g2 < 2; ++g2) {
    float s = runc[g2];
    s += __shfl_xor(s, 16);
    s += __shfl_xor(s, 32);
    if (quad == 0)
      pc[((long)b * 2 + seg) * 2048 + m0 + g2 * 64 + wave * 16 + l15] = s;
  }
  // PV partials
  float* pa = pacc + ((long)b * 2 + seg) * 262144;
  #pragma unroll
  for (int g2 = 0; g2 < 2; ++g2)
    #pragma unroll
    for (int dt = 0; dt < 8; ++dt) {
      int d = dt * 16 + l15;
      #pragma unroll
      for (int r = 0; r < 4; ++r)
        pa[(long)(m0 + g2 * 64 + wave * 16 + quad * 4 + r) * 128 + d] = acc[g2][dt][r];
    }
}

// combine PV partials: xrb = bf16(li - (P0+P1)/(1e-9+c0+c1)). grid (256, g).
__global__ __launch_bounds__(256)
void pvred_k(const float* __restrict__ pacc, const float* __restrict__ pc,
             const unsigned short* __restrict__ lib, long sLi, int ldLi,
             unsigned short* __restrict__ xrb, long sXr) {
  int i = blockIdx.x * 256 + threadIdx.x;
  int b = blockIdx.y;
  int m = i >> 5, d4 = (i & 31) * 4;
  float4 a0 = *(const float4*)&pacc[((long)b * 2 + 0) * 262144 + (long)m * 128 + d4];
  float4 a1 = *(const float4*)&pacc[((long)b * 2 + 1) * 262144 + (long)m * 128 + d4];
  float c = pc[((long)b * 2) * 2048 + m] + pc[((long)b * 2 + 1) * 2048 + m];
  float inv = 1.f / (1e-9f + c);
  uint2 lv = *(const uint2*)&lib[(long)b * sLi + (long)m * ldLi + d4];
  unsigned short lr[4];
  *(uint2*)lr = lv;
  unsigned short o[4];
  o[0] = f2bf(bf2f(lr[0]) - (a0.x + a1.x) * inv);
  o[1] = f2bf(bf2f(lr[1]) - (a0.y + a1.y) * inv);
  o[2] = f2bf(bf2f(lr[2]) - (a0.z + a1.z) * inv);
  o[3] = f2bf(bf2f(lr[3]) - (a0.w + a1.w) * inv);
  *(uint2*)&xrb[(long)b * sXr + (long)m * 128 + d4] = *(uint2*)&o[0];
}

// ---------------------------------------------------------------------------
__global__ void poolred_k(const float* __restrict__ pmax, const float* __restrict__ psum,
                          float* __restrict__ xmax, float* __restrict__ xavg) {
  int f = blockIdx.x * 256 + threadIdx.x, b = blockIdx.y;
  float mx = -1e30f, s = 0.f;
  #pragma unroll
  for (int t = 0; t < 16; ++t) {
    mx = fmaxf(mx, pmax[((long)b * 16 + t) * 1024 + f]);
    s += psum[((long)b * 16 + t) * 1024 + f];
  }
  xmax[(long)b * 1024 + f] = mx;
  xavg[(long)b * 1024 + f] = s * (1.f / 2048.f);
}

// pt[b][o] = sc1[o] * ( ws1[o][1024:2048].xmax + ws1[o][2048:3072].xavg )
__global__ __launch_bounds__(256)
void poolterm_k(const float* __restrict__ ws1, const float* __restrict__ xmax,
                const float* __restrict__ xavg,
                const float* __restrict__ bg, const float* __restrict__ bv,
                float* __restrict__ pt) {
  int o = blockIdx.x, b = blockIdx.y, tid = threadIdx.x;
  const float* w = ws1 + (long)o * 3072;
  float s = 0.f;
  #pragma unroll
  for (int it = 0; it < 4; ++it) {
    int c = tid + it * 256;
    s += w[1024 + c] * xmax[(long)b * 1024 + c] + w[2048 + c] * xavg[(long)b * 1024 + c];
  }
  #pragma unroll
  for (int off = 32; off; off >>= 1) s += __shfl_xor(s, off);
  __shared__ float rsm[4];
  if ((tid & 63) == 0) rsm[tid >> 6] = s;
  __syncthreads();
  if (tid == 0) {
    float sc = bg[o] * rsqrtf(bv[o] + BN_EPS);
    pt[(long)b * H1_ + o] = sc * (rsm[0] + rsm[1] + rsm[2] + rsm[3]);
  }
}

// ---------------------------------------------------------------------------
extern "C" void kernel_launch(void* const* d_in, const int* in_sizes, int n_in,
                              void* d_out, int out_size, void* d_ws, size_t ws_size,
                              hipStream_t stream) {
  const float* x      = (const float*)d_in[0];
  const float* w1     = (const float*)d_in[1];
  const float* w2     = (const float*)d_in[2];
  const float* bn1_g  = (const float*)d_in[3];
  const float* bn1_b  = (const float*)d_in[4];
  const float* bn1_m  = (const float*)d_in[5];
  const float* bn1_v  = (const float*)d_in[6];
  const float* bn2_g  = (const float*)d_in[7];
  const float* bn2_b  = (const float*)d_in[8];
  const float* bn2_m  = (const float*)d_in[9];
  const float* bn2_v  = (const float*)d_in[10];
  const float* sa_wqk = (const float*)d_in[11];
  const float* sa_wv  = (const float*)d_in[12];
  const float* sa_bv  = (const float*)d_in[13];
  const float* sa_wt  = (const float*)d_in[14];
  const float* sa_bt  = (const float*)d_in[15];
  const float* sa_g   = (const float*)d_in[16];
  const float* sa_b   = (const float*)d_in[17];
  const float* sa_m   = (const float*)d_in[18];
  const float* sa_v   = (const float*)d_in[19];
  const float* wf     = (const float*)d_in[20];
  const float* bnf_g  = (const float*)d_in[21];
  const float* bnf_b  = (const float*)d_in[22];
  const float* bnf_m  = (const float*)d_in[23];
  const float* bnf_v  = (const float*)d_in[24];
  const float* ws1    = (const float*)d_in[25];
  const float* bs1    = (const float*)d_in[26];
  const float* bns1_g = (const float*)d_in[27];
  const float* bns1_b = (const float*)d_in[28];
  const float* bns1_m = (const float*)d_in[29];
  const float* bns1_v = (const float*)d_in[30];
  const float* ws2    = (const float*)d_in[31];
  const float* bs2    = (const float*)d_in[32];
  const float* bns2_g = (const float*)d_in[33];
  const float* bns2_b = (const float*)d_in[34];
  const float* bns2_m = (const float*)d_in[35];
  const float* bns2_v = (const float*)d_in[36];
  float* out = (float*)d_out;

  float* ws = (float*)d_ws;
  size_t off = 0;
  auto alloc  = [&](size_t n) { float* p = ws + off; off += (n + 63) & ~(size_t)63; return p; };
  auto allocH = [&](size_t n) { return (unsigned short*)alloc((n + 1) / 2); };

  unsigned short* w2b  = allocH(128 * 128);
  unsigned short* wqkb = allocH(4 * 128 * 128);
  unsigned short* wvb  = allocH(4 * 128 * 128);
  unsigned short* wtb  = allocH(4 * 128 * 128);
  unsigned short* wfb  = allocH((size_t)F_ * 512);
  unsigned short* ws1b = allocH((size_t)H1_ * 1024);
  unsigned short* ws2b = allocH((size_t)128 * 512);
  float* bias_w2 = alloc(128);
  float* bias_v  = alloc(512);
  float* bias_t  = alloc(512);
  float* bias_f  = alloc(1024);
  float* bias_s1 = alloc(512);
  float* bias_s2 = alloc(128);
  float* lwB  = alloc((size_t)16 * 2048);
  float* pmax = alloc((size_t)16 * 16 * 1024);
  float* psum = alloc((size_t)16 * 16 * 1024);
  float* xmaxB = alloc((size_t)16 * 1024);
  float* xavgB = alloc((size_t)16 * 1024);
  float* ptB   = alloc((size_t)16 * 512);
  size_t fixedOff = off;

  // per-batch (floats): h1b 131072 + featsb 524288 + fusedb 1048576 +
  //   xkb/xvb/xrb 3*131072 + pacc 524288 + pm/ps/pc 3*4096
  const size_t perB = 131072 + 524288 + 1048576 + 131072 + 131072 + 131072 +
                      524288 + 12288;
  size_t wsFloats = ws_size / 4;
  int Gb = 1;
  for (int c : {16, 8, 4, 2, 1}) {
    if (fixedOff + (size_t)c * perB + 4096 <= wsFloats) { Gb = c; break; }
  }

  unsigned short* h1b    = allocH((size_t)Gb * 262144);
  unsigned short* featsb = allocH((size_t)Gb * 1048576);   // hs1b aliases
  unsigned short* fusedb = allocH((size_t)Gb * 2097152);
  unsigned short* xkb    = allocH((size_t)Gb * 262144);
  unsigned short* xvb    = allocH((size_t)Gb * 262144);
  unsigned short* xrb    = allocH((size_t)Gb * 262144);    // h0b aliases
  float* paccB = alloc((size_t)Gb * 2 * 262144);
  float* pmB   = alloc((size_t)Gb * 2 * 2048);
  float* psB   = alloc((size_t)Gb * 2 * 2048);
  float* pcB   = alloc((size_t)Gb * 2 * 2048);
  unsigned short* h0b  = xrb;
  unsigned short* hs1b = featsb;

  foldw_k<<<64, 256, 0, stream>>>(w2, 128, nullptr, bn2_g, bn2_b, bn2_m, bn2_v,
                                  w2b, bias_w2, 128, 128, 128);
  for (int i = 0; i < 4; ++i) {
    foldw_k<<<64, 256, 0, stream>>>(sa_wqk + (size_t)i * 16384, 128, nullptr,
                                    nullptr, nullptr, nullptr, nullptr,
                                    wqkb + (size_t)i * 16384, nullptr, 128, 128, 128);
    foldw_k<<<64, 256, 0, stream>>>(sa_wv + (size_t)i * 16384, 128, sa_bv + i * 128,
                                    nullptr, nullptr, nullptr, nullptr,
                                    wvb + (size_t)i * 16384, bias_v + i * 128, 128, 128, 128);
    foldw_k<<<64, 256, 0, stream>>>(sa_wt + (size_t)i * 16384, 128, sa_bt + i * 128,
                                    sa_g + i * 128, sa_b + i * 128, sa_m + i * 128, sa_v + i * 128,
                                    wtb + (size_t)i * 16384, bias_t + i * 128, 128, 128, 128);
  }
  foldw_k<<<2048, 256, 0, stream>>>(wf, 512, nullptr, bnf_g, bnf_b, bnf_m, bnf_v,
                                    wfb, bias_f, 1024, 1024, 512);
  foldw_k<<<2048, 256, 0, stream>>>(ws1, 3072, bs1, bns1_g, bns1_b, bns1_m, bns1_v,
                                    ws1b, bias_s1, 512, 512, 1024);
  foldw_k<<<256, 256, 0, stream>>>(ws2, 512, bs2, bns2_g, bns2_b, bns2_m, bns2_v,
                                   ws2b, bias_s2, 50, 128, 512);

  const long sAct = 262144, sFeat = 1048576, sFus = 2097152;
  for (int b0 = 0; b0 < B_; b0 += Gb) {
    int g = Gb;
    conv1_k<<<dim3(N_, g), 128, 0, stream>>>(x + (long)b0 * 3 * N_, w1,
                                             bn1_g, bn1_b, bn1_m, bn1_v, h0b);
    // conv2+bn2+relu -> h1b bf16
    gemm_tok<64><<<dim3(32, 1, g), 256, 0, stream>>>(
        w2b, 128, h0b, sAct, 128, bias_w2, nullptr, 0, nullptr, 0, 0,
        h1b, sAct, 128, nullptr, nullptr, 128, 1, 0);

    for (int i = 0; i < 4; ++i) {
      const unsigned short* lib = (i == 0) ? h1b : featsb + (size_t)(i - 1) * 128;
      int ldLi = (i == 0) ? 128 : 512;
      long sLi = (i == 0) ? sAct : sFeat;
      // xk (bf16 token)
      gemm_tok<64><<<dim3(32, 1, g), 256, 0, stream>>>(
          wqkb + (size_t)i * 16384, 128, lib, sLi, ldLi, nullptr, nullptr, 0,
          nullptr, 0, 0, xkb, sAct, 128, nullptr, nullptr, 128, 0, 0);
      // xv (bf16 channel, +bv)
      gemm_chan<64><<<dim3(32, 1, g), 256, 0, stream>>>(
          wvb + (size_t)i * 16384, 128, lib, sLi, ldLi, bias_v + i * 128,
          nullptr, 0, 0, xvb, sAct, 2048, 128, 128, 0);
      gram_lw<<<dim3(g, 16, 2), 256, 0, stream>>>(xkb, sAct, pmB, psB);
      lwred_k<<<dim3(8, g), 256, 0, stream>>>(pmB, psB, lwB);
      pv_k<<<dim3(g, 16, 2), 256, 0, stream>>>(xkb, sAct, xvb, sAct, lwB, paccB, pcB);
      pvred_k<<<dim3(256, g), 256, 0, stream>>>(paccB, pcB, lib, sLi, ldLi, xrb, sAct);
      // feats_i = li + relu(wt' @ (li - xr) + bt')   (res = bf16 li)
      gemm_tok<64><<<dim3(32, 1, g), 256, 0, stream>>>(
          wtb + (size_t)i * 16384, 128, xrb, sAct, 128, bias_t + i * 128, nullptr, 0,
          lib, sLi, ldLi,
          featsb + (size_t)i * 128, sFeat, 512, nullptr, nullptr, 128, 1, 16);
    }

    // fused = leaky(wf' @ feats + bf') -> bf16 + pool partials
    gemm_tok<128><<<dim3(16, 8, g), 256, 0, stream>>>(
        wfb, 512, featsb, sFeat, 512, bias_f, nullptr, 0, nullptr, 0, 0,
        fusedb, sFus, 1024, pmax, psum, 512, 2, 32);
    poolred_k<<<dim3(4, g), 256, 0, stream>>>(pmax, psum, xmaxB, xavgB);
    poolterm_k<<<dim3(512, g), 256, 0, stream>>>(ws1, xmaxB, xavgB, bns1_g, bns1_v, ptB);
    // hs1 = relu(ws1' @ fused + bs1' + pt) -> bf16
    gemm_tok<128><<<dim3(16, 4, g), 256, 0, stream>>>(
        ws1b, 1024, fusedb, sFus, 1024, bias_s1, ptB, 512, nullptr, 0, 0,
        hs1b, sFeat, 512, nullptr, nullptr, 1024, 1, 0);
    // out = relu(ws2' @ hs1 + bs2') -> fp32 channel-major
    gemm_chan<64><<<dim3(32, 1, g), 256, 0, stream>>>(
        ws2b, 512, hs1b, sFeat, 512, bias_s2,
        out + (long)b0 * OUT_ * N_, (long)OUT_ * N_, 2048, nullptr, 0, 0,
        512, 50, 1);
  }
}

// Round 14
// 702.964 us; speedup vs baseline: 1.5736x; 1.0831x over previous
//
#include <hip/hip_runtime.h>
#include <cstdint>
#include <cstddef>

#define B_   16
#define N_   2048
#define D_   128
#define F_   1024
#define H1_  512
#define OUT_ 50

static constexpr float BN_EPS = 1e-5f;

typedef __attribute__((ext_vector_type(8))) short short8;
typedef __attribute__((ext_vector_type(4))) float f32x4;

__device__ inline unsigned short f2bf(float f) {
  union { float f; unsigned u; } v; v.f = f;
  unsigned r = v.u + 0x7fff + ((v.u >> 16) & 1);
  return (unsigned short)(r >> 16);
}
__device__ inline float bf2f(unsigned short h) {
  union { unsigned u; float f; } v; v.u = ((unsigned)h) << 16; return v.f;
}

// async global->LDS, 16B per lane; LDS dest = wave-uniform base + lane*16
__device__ inline void dma16(const unsigned short* g, unsigned short* l) {
  __builtin_amdgcn_global_load_lds(
      (const __attribute__((address_space(1))) unsigned int*)g,
      (__attribute__((address_space(3))) unsigned int*)l, 16, 0, 0);
}

// ---------------------------------------------------------------------------
// Fold BN (+bias) into bf16 weights + fp32 bias.
// ---------------------------------------------------------------------------
__global__ void foldw_k(const float* __restrict__ W, int ldW,
                        const float* __restrict__ bias,
                        const float* __restrict__ g, const float* __restrict__ bb,
                        const float* __restrict__ m, const float* __restrict__ v,
                        unsigned short* __restrict__ Wb, float* __restrict__ biasF,
                        int O, int Opad, int K) {
  long i = (long)blockIdx.x * 256 + threadIdx.x;
  if (i >= (long)Opad * K) return;
  int o = (int)(i / K), k = (int)(i % K);
  float sc = 1.f, sh = 0.f;
  if (o < O && g) { sc = g[o] * rsqrtf(v[o] + BN_EPS); sh = bb[o] - m[o] * sc; }
  float w = (o < O) ? W[(long)o * ldW + k] * sc : 0.f;
  Wb[i] = f2bf(w);
  if (k == 0 && biasF) {
    float bf = 0.f;
    if (o < O) bf = (bias ? bias[o] : 0.f) * sc + sh;
    biasF[o] = bf;
  }
}

// ---------------------------------------------------------------------------
// conv1 (3->128) + bn + relu -> bf16 token-major. grid (N, g), block 128
// ---------------------------------------------------------------------------
__global__ void conv1_k(const float* __restrict__ x, const float* __restrict__ w1,
                        const float* __restrict__ g, const float* __restrict__ bb,
                        const float* __restrict__ m, const float* __restrict__ v,
                        unsigned short* __restrict__ h0b) {
  int o = threadIdx.x, n = blockIdx.x, b = blockIdx.y;
  const float* xb = x + (long)b * 3 * N_;
  float val = w1[o * 3 + 0] * xb[n] + w1[o * 3 + 1] * xb[N_ + n] + w1[o * 3 + 2] * xb[2 * N_ + n];
  float sc = g[o] * rsqrtf(v[o] + BN_EPS);
  val = val * sc + (bb[o] - m[o] * sc);
  h0b[((long)b * N_ + n) * D_ + o] = f2bf(fmaxf(val, 0.f));
}

// ---------------------------------------------------------------------------
// Token-output MFMA GEMM (swapped operands): out[n][o] bf16, O mult of 128.
// Tile TM x 128, BK=64, block 256 (2x2 waves). DMA staging + XOR swizzle.
// Epilogue: LDS repack -> 256B-row vector stores.
// flags: 16 add bf16 res after act | 32 pool partials
// ---------------------------------------------------------------------------
template <int TM>
__global__ __launch_bounds__(256, 4)
void gemm_tok(const unsigned short* __restrict__ Wb, int ldW,
              const unsigned short* __restrict__ A, long sA, int ldA,
              const float* __restrict__ biasF,
              const float* __restrict__ perBO, int ldPBO,
              const unsigned short* __restrict__ resH, long sRes, int ldRes,
              unsigned short* __restrict__ outH, long sOutH, int ldOutH,
              float* __restrict__ pmax, float* __restrict__ psum,
              int K, int act, int flags) {
  constexpr int MT = (TM + 31) / 32;
  __shared__ unsigned short lAB[TM * 64 + 128 * 64];
  __shared__ float lpm[4][64], lps[4][64];
  unsigned short* lA = lAB;
  unsigned short* lB = lAB + TM * 64;
  unsigned short* lS = lAB;                 // repack tile TM x 128 (aliases)
  int tid = threadIdx.x;
  int n0 = blockIdx.x * TM, o0 = blockIdx.y * 128, b = blockIdx.z;
  int wave = tid >> 6, lane = tid & 63;
  int wr = wave >> 1, wc = wave & 1;
  int quad = lane >> 4, l15 = lane & 15;
  int rowL = lane >> 3;
  int kseg = (lane & 7) ^ rowL;
  const unsigned short* Ab = A + (long)b * sA + (long)n0 * ldA;
  const unsigned short* Wp = Wb + (long)o0 * ldW;

  f32x4 acc[MT][4];
  #pragma unroll
  for (int i = 0; i < MT; ++i)
    #pragma unroll
    for (int j = 0; j < 4; ++j) acc[i][j] = (f32x4){0.f, 0.f, 0.f, 0.f};

  for (int kc = 0; kc < K; kc += 64) {
    #pragma unroll
    for (int t = 0; t < 4; ++t) {
      int chunk = t * 4 + wave;
      dma16(Wp + (long)(chunk * 8 + rowL) * ldW + kc + kseg * 8, &lB[chunk * 512]);
      if (chunk < TM / 8)
        dma16(Ab + (long)(chunk * 8 + rowL) * ldA + kc + kseg * 8, &lA[chunk * 512]);
    }
    __syncthreads();
    #pragma unroll
    for (int kk = 0; kk < 2; ++kk) {
      short8 af[MT], bf[4];
      #pragma unroll
      for (int mt = 0; mt < MT; ++mt) {
        int r = wr * (TM / 2) + mt * 16 + l15;
        af[mt] = *(const short8*)&lA[r * 64 + (((kk * 4 + quad) ^ (l15 & 7)) * 8)];
      }
      #pragma unroll
      for (int ot = 0; ot < 4; ++ot) {
        int r = wc * 64 + ot * 16 + l15;
        bf[ot] = *(const short8*)&lB[r * 64 + (((kk * 4 + quad) ^ (l15 & 7)) * 8)];
      }
      #pragma unroll
      for (int mt = 0; mt < MT; ++mt)
        #pragma unroll
        for (int ot = 0; ot < 4; ++ot)
          acc[mt][ot] = __builtin_amdgcn_mfma_f32_16x16x32_bf16(bf[ot], af[mt], acc[mt][ot], 0, 0, 0);
    }
    __syncthreads();
  }

  bool doPool = (flags & 32) != 0;
  #pragma unroll
  for (int ot = 0; ot < 4; ++ot) {
    int obL = wc * 64 + ot * 16 + quad * 4;
    int ob = o0 + obL;
    float bi[4] = {0.f, 0.f, 0.f, 0.f};
    if (biasF) { float4 t = *(const float4*)&biasF[ob]; bi[0] = t.x; bi[1] = t.y; bi[2] = t.z; bi[3] = t.w; }
    if (perBO) {
      float4 t = *(const float4*)&perBO[(long)b * ldPBO + ob];
      bi[0] += t.x; bi[1] += t.y; bi[2] += t.z; bi[3] += t.w;
    }
    float pm4[4], ps4[4];
    #pragma unroll
    for (int r = 0; r < 4; ++r) { pm4[r] = -1e30f; ps4[r] = 0.f; }
    int g = obL >> 3, go = obL & 7;
    #pragma unroll
    for (int mt = 0; mt < MT; ++mt) {
      int nL = wr * (TM / 2) + mt * 16 + l15;
      float vals[4];
      #pragma unroll
      for (int r = 0; r < 4; ++r) {
        float val = acc[mt][ot][r] + bi[r];
        if (act == 1)      val = fmaxf(val, 0.f);
        else if (act == 2) val = (val >= 0.f) ? val : 0.2f * val;
        vals[r] = val;
      }
      if (flags & 16) {
        uint2 rv = *(const uint2*)&resH[(long)b * sRes + (long)(n0 + nL) * ldRes + ob];
        unsigned short rr[4];
        *(uint2*)rr = rv;
        #pragma unroll
        for (int r = 0; r < 4; ++r) vals[r] += bf2f(rr[r]);
      }
      unsigned short t4[4];
      #pragma unroll
      for (int r = 0; r < 4; ++r) {
        t4[r] = f2bf(vals[r]);
        if (doPool) { pm4[r] = fmaxf(pm4[r], vals[r]); ps4[r] += vals[r]; }
      }
      int gp = (g & 8) | ((g ^ (nL & 7)) & 7);
      *(uint2*)&lS[nL * 128 + gp * 8 + go] = *(uint2*)&t4[0];
    }
    if (doPool) {
      #pragma unroll
      for (int r = 0; r < 4; ++r) {
        float m = pm4[r], s = ps4[r];
        m = fmaxf(m, __shfl_xor(m, 1)); s += __shfl_xor(s, 1);
        m = fmaxf(m, __shfl_xor(m, 2)); s += __shfl_xor(s, 2);
        m = fmaxf(m, __shfl_xor(m, 4)); s += __shfl_xor(s, 4);
        m = fmaxf(m, __shfl_xor(m, 8)); s += __shfl_xor(s, 8);
        if (l15 == 0) { lpm[wave][ot * 16 + quad * 4 + r] = m; lps[wave][ot * 16 + quad * 4 + r] = s; }
      }
    }
  }
  __syncthreads();
  {
    int r0 = tid >> 4, s = tid & 15;
    #pragma unroll
    for (int it = 0; it < TM / 16; ++it) {
      int row = it * 16 + r0;
      int sp = (s & 8) | ((s ^ (row & 7)) & 7);
      short8 v = *(const short8*)&lS[row * 128 + sp * 8];
      *(short8*)&outH[(long)b * sOutH + (long)(n0 + row) * ldOutH + o0 + s * 8] = v;
    }
  }
  if (doPool && tid < 128) {
    int wcx = tid >> 6, ol = tid & 63;
    float m = fmaxf(lpm[wcx][ol], lpm[wcx + 2][ol]);
    float s = lps[wcx][ol] + lps[wcx + 2][ol];
    int o = o0 + wcx * 64 + ol;
    pmax[((long)b * 16 + blockIdx.x) * 1024 + o] = m;
    psum[((long)b * 16 + blockIdx.x) * 1024 + o] = s;
  }
}

// ---------------------------------------------------------------------------
// Channel-output MFMA GEMM (unswapped): out[o][n] fp32 or bf16; O guarded.
// ---------------------------------------------------------------------------
template <int TM>
__global__ __launch_bounds__(256, 4)
void gemm_chan(const unsigned short* __restrict__ Wb, int ldW,
               const unsigned short* __restrict__ A, long sA, int ldA,
               const float* __restrict__ biasF,
               float* __restrict__ outF, long sOutF, int ldOutF,
               unsigned short* __restrict__ outH, long sOutH, int ldOutH,
               int K, int O, int act) {
  constexpr int MT = (TM + 31) / 32;
  __shared__ unsigned short lA[TM * 64];
  __shared__ unsigned short lB[128 * 64];
  int tid = threadIdx.x;
  int n0 = blockIdx.x * TM, o0 = blockIdx.y * 128, b = blockIdx.z;
  int wave = tid >> 6, lane = tid & 63;
  int wr = wave >> 1, wc = wave & 1;
  int quad = lane >> 4, l15 = lane & 15;
  int rowL = lane >> 3;
  int kseg = (lane & 7) ^ rowL;
  const unsigned short* Ab = A + (long)b * sA + (long)n0 * ldA;
  const unsigned short* Wp = Wb + (long)o0 * ldW;

  f32x4 acc[MT][4];
  #pragma unroll
  for (int i = 0; i < MT; ++i)
    #pragma unroll
    for (int j = 0; j < 4; ++j) acc[i][j] = (f32x4){0.f, 0.f, 0.f, 0.f};

  for (int kc = 0; kc < K; kc += 64) {
    #pragma unroll
    for (int t = 0; t < 4; ++t) {
      int chunk = t * 4 + wave;
      dma16(Wp + (long)(chunk * 8 + rowL) * ldW + kc + kseg * 8, &lB[chunk * 512]);
      if (chunk < TM / 8)
        dma16(Ab + (long)(chunk * 8 + rowL) * ldA + kc + kseg * 8, &lA[chunk * 512]);
    }
    __syncthreads();
    #pragma unroll
    for (int kk = 0; kk < 2; ++kk) {
      short8 af[MT], bf[4];
      #pragma unroll
      for (int mt = 0; mt < MT; ++mt) {
        int r = wr * (TM / 2) + mt * 16 + l15;
        af[mt] = *(const short8*)&lA[r * 64 + (((kk * 4 + quad) ^ (l15 & 7)) * 8)];
      }
      #pragma unroll
      for (int ot = 0; ot < 4; ++ot) {
        int r = wc * 64 + ot * 16 + l15;
        bf[ot] = *(const short8*)&lB[r * 64 + (((kk * 4 + quad) ^ (l15 & 7)) * 8)];
      }
      #pragma unroll
      for (int mt = 0; mt < MT; ++mt)
        #pragma unroll
        for (int ot = 0; ot < 4; ++ot)
          acc[mt][ot] = __builtin_amdgcn_mfma_f32_16x16x32_bf16(af[mt], bf[ot], acc[mt][ot], 0, 0, 0);
    }
    __syncthreads();
  }

  #pragma unroll
  for (int ot = 0; ot < 4; ++ot) {
    int o = o0 + wc * 64 + ot * 16 + l15;
    if (o >= O) continue;
    float bi = biasF ? biasF[o] : 0.f;
    #pragma unroll
    for (int mt = 0; mt < MT; ++mt) {
      int nb = n0 + wr * (TM / 2) + mt * 16 + quad * 4;
      float vals[4];
      #pragma unroll
      for (int r = 0; r < 4; ++r) {
        float val = acc[mt][ot][r] + bi;
        if (act == 1)      val = fmaxf(val, 0.f);
        else if (act == 2) val = (val >= 0.f) ? val : 0.2f * val;
        vals[r] = val;
      }
      if (outF)
        *(float4*)&outF[(long)b * sOutF + (long)o * ldOutF + nb] = *(float4*)vals;
      if (outH) {
        unsigned short t[4];
        #pragma unroll
        for (int r = 0; r < 4; ++r) t[r] = f2bf(vals[r]);
        *(uint2*)&outH[(long)b * sOutH + (long)o * ldOutH + nb] = *(uint2*)&t[0];
      }
    }
  }
}

// ---------------------------------------------------------------------------
// Fused xk+xv: grid (32, 2, g). y=0: xk = wqk@li, token bf16 (swapped+repack).
// y=1: xv = wv@li + bv, channel bf16 (unswapped). K=128, tile 64x128.
// ---------------------------------------------------------------------------
__global__ __launch_bounds__(256, 4)
void gemm_kv(const unsigned short* __restrict__ Wqk, const unsigned short* __restrict__ Wv,
             const float* __restrict__ biasV,
             const unsigned short* __restrict__ A, long sA, int ldA,
             unsigned short* __restrict__ xk, long sXk,
             unsigned short* __restrict__ xv, long sXv) {
  __shared__ unsigned short lAB[64 * 64 + 128 * 64];
  unsigned short* lA = lAB;
  unsigned short* lB = lAB + 64 * 64;
  unsigned short* lS = lAB;
  int tid = threadIdx.x;
  int n0 = blockIdx.x * 64, path = blockIdx.y, b = blockIdx.z;
  int wave = tid >> 6, lane = tid & 63;
  int wr = wave >> 1, wc = wave & 1;
  int quad = lane >> 4, l15 = lane & 15;
  int rowL = lane >> 3;
  int kseg = (lane & 7) ^ rowL;
  const unsigned short* Ab = A + (long)b * sA + (long)n0 * ldA;
  const unsigned short* Wp = path ? Wv : Wqk;

  f32x4 acc[2][4];
  #pragma unroll
  for (int i = 0; i < 2; ++i)
    #pragma unroll
    for (int j = 0; j < 4; ++j) acc[i][j] = (f32x4){0.f, 0.f, 0.f, 0.f};

  for (int kc = 0; kc < 128; kc += 64) {
    #pragma unroll
    for (int t = 0; t < 4; ++t) {
      int chunk = t * 4 + wave;
      dma16(Wp + (long)(chunk * 8 + rowL) * 128 + kc + kseg * 8, &lB[chunk * 512]);
      if (chunk < 8)
        dma16(Ab + (long)(chunk * 8 + rowL) * ldA + kc + kseg * 8, &lA[chunk * 512]);
    }
    __syncthreads();
    #pragma unroll
    for (int kk = 0; kk < 2; ++kk) {
      short8 af[2], bf[4];
      #pragma unroll
      for (int mt = 0; mt < 2; ++mt) {
        int r = wr * 32 + mt * 16 + l15;
        af[mt] = *(const short8*)&lA[r * 64 + (((kk * 4 + quad) ^ (l15 & 7)) * 8)];
      }
      #pragma unroll
      for (int ot = 0; ot < 4; ++ot) {
        int r = wc * 64 + ot * 16 + l15;
        bf[ot] = *(const short8*)&lB[r * 64 + (((kk * 4 + quad) ^ (l15 & 7)) * 8)];
      }
      if (path == 0) {
        #pragma unroll
        for (int mt = 0; mt < 2; ++mt)
          #pragma unroll
          for (int ot = 0; ot < 4; ++ot)
            acc[mt][ot] = __builtin_amdgcn_mfma_f32_16x16x32_bf16(bf[ot], af[mt], acc[mt][ot], 0, 0, 0);
      } else {
        #pragma unroll
        for (int mt = 0; mt < 2; ++mt)
          #pragma unroll
          for (int ot = 0; ot < 4; ++ot)
            acc[mt][ot] = __builtin_amdgcn_mfma_f32_16x16x32_bf16(af[mt], bf[ot], acc[mt][ot], 0, 0, 0);
      }
    }
    __syncthreads();
  }

  if (path == 0) {
    // token repack -> xk
    #pragma unroll
    for (int ot = 0; ot < 4; ++ot) {
      int obL = wc * 64 + ot * 16 + quad * 4;
      int g = obL >> 3, go = obL & 7;
      #pragma unroll
      for (int mt = 0; mt < 2; ++mt) {
        int nL = wr * 32 + mt * 16 + l15;
        unsigned short t4[4];
        #pragma unroll
        for (int r = 0; r < 4; ++r) t4[r] = f2bf(acc[mt][ot][r]);
        int gp = (g & 8) | ((g ^ (nL & 7)) & 7);
        *(uint2*)&lS[nL * 128 + gp * 8 + go] = *(uint2*)&t4[0];
      }
    }
    __syncthreads();
    int r0 = tid >> 4, s = tid & 15;
    #pragma unroll
    for (int it = 0; it < 4; ++it) {
      int row = it * 16 + r0;
      int sp = (s & 8) | ((s ^ (row & 7)) & 7);
      short8 v = *(const short8*)&lS[row * 128 + sp * 8];
      *(short8*)&xk[(long)b * sXk + (long)(n0 + row) * 128 + s * 8] = v;
    }
  } else {
    // channel -> xv with bias
    #pragma unroll
    for (int ot = 0; ot < 4; ++ot) {
      int o = wc * 64 + ot * 16 + l15;
      float bi = biasV[o];
      #pragma unroll
      for (int mt = 0; mt < 2; ++mt) {
        int nb = n0 + wr * 32 + mt * 16 + quad * 4;
        unsigned short t[4];
        #pragma unroll
        for (int r = 0; r < 4; ++r) t[r] = f2bf(acc[mt][ot][r] + bi);
        *(uint2*)&xv[(long)b * sXv + (long)o * 2048 + nb] = *(uint2*)&t[0];
      }
    }
  }
}

// ---------------------------------------------------------------------------
// Gram row-stats, split-M, 2 n-groups/wave (each lK read feeds 2 MFMAs).
// Block n-tile 128. seg: m in [seg*1024, seg*1024+1024).
// grid (g, 16, 2): b fastest -> XCD = b%8. Dbuf LDS, 1 barrier/chunk.
// ---------------------------------------------------------------------------
__global__ __launch_bounds__(256)
void gram_lw(const unsigned short* __restrict__ xk, long sXk,
             float* __restrict__ pm, float* __restrict__ ps) {
  __shared__ unsigned short lK[2][64 * 128];
  int tid = threadIdx.x, wave = tid >> 6, lane = tid & 63;
  int quad = lane >> 4, l15 = lane & 15;
  int rowL4 = lane >> 4, s16 = lane & 15;
  int n0 = blockIdx.y * 128, b = blockIdx.x, seg = blockIdx.z;
  int mbase = seg * 1024;
  const unsigned short* Kp = xk + (long)b * sXk;
  short8 afr[2][4];
  #pragma unroll
  for (int g2 = 0; g2 < 2; ++g2) {
    const unsigned short* arow = Kp + (long)(n0 + g2 * 64 + wave * 16 + l15) * 128;
    #pragma unroll
    for (int kf = 0; kf < 4; ++kf) afr[g2][kf] = *(const short8*)(arow + kf * 32 + quad * 8);
  }
  float runm[2][4], runs[2][4];
  #pragma unroll
  for (int g2 = 0; g2 < 2; ++g2)
    #pragma unroll
    for (int r = 0; r < 4; ++r) { runm[g2][r] = -1e30f; runs[g2][r] = 0.f; }

  auto stage = [&](int ch, int bf) {
    #pragma unroll
    for (int t = 0; t < 4; ++t) {
      int c = t * 4 + wave;
      int row = c * 4 + rowL4;
      int gseg = (s16 & 8) | ((s16 ^ (row & 7)) & 7);
      dma16(Kp + (long)(mbase + ch * 64 + row) * 128 + gseg * 8, &lK[bf][c * 512]);
    }
  };
  stage(0, 0);

  for (int ch = 0; ch < 16; ++ch) {
    __syncthreads();
    int bf = ch & 1;
    if (ch + 1 < 16) stage(ch + 1, bf ^ 1);
    f32x4 sv[2][4];
    #pragma unroll
    for (int mf = 0; mf < 4; ++mf) {
      f32x4 sa = (f32x4){0.f, 0.f, 0.f, 0.f};
      f32x4 sb = (f32x4){0.f, 0.f, 0.f, 0.f};
      #pragma unroll
      for (int kf = 0; kf < 4; ++kf) {
        int r = mf * 16 + l15, q = kf * 4 + quad;
        int sp = (q & 8) | ((q ^ (r & 7)) & 7);
        short8 bfr = *(const short8*)&lK[bf][r * 128 + sp * 8];
        sa = __builtin_amdgcn_mfma_f32_16x16x32_bf16(afr[0][kf], bfr, sa, 0, 0, 0);
        sb = __builtin_amdgcn_mfma_f32_16x16x32_bf16(afr[1][kf], bfr, sb, 0, 0, 0);
      }
      sv[0][mf] = sa; sv[1][mf] = sb;
    }
    #pragma unroll
    for (int g2 = 0; g2 < 2; ++g2)
      #pragma unroll
      for (int r = 0; r < 4; ++r) {
        float e0 = sv[g2][0][r], e1 = sv[g2][1][r], e2 = sv[g2][2][r], e3 = sv[g2][3][r];
        float cm = fmaxf(fmaxf(e0, e1), fmaxf(e2, e3));
        float mn = fmaxf(runm[g2][r], cm);
        runs[g2][r] = runs[g2][r] * __expf(runm[g2][r] - mn) +
                      (__expf(e0 - mn) + __expf(e1 - mn)) + (__expf(e2 - mn) + __expf(e3 - mn));
        runm[g2][r] = mn;
      }
  }
  #pragma unroll
  for (int g2 = 0; g2 < 2; ++g2)
    #pragma unroll
    for (int r = 0; r < 4; ++r) {
      float m = runm[g2][r], s = runs[g2][r];
      #pragma unroll
      for (int off = 1; off < 16; off <<= 1) {
        float mo = __shfl_xor(m, off), so = __shfl_xor(s, off);
        float mn = fmaxf(m, mo);
        s = s * __expf(m - mn) + so * __expf(mo - mn);
        m = mn;
      }
      if (l15 == 0) {
        int n = n0 + g2 * 64 + wave * 16 + quad * 4 + r;
        pm[((long)b * 2 + seg) * 2048 + n] = m;
        ps[((long)b * 2 + seg) * 2048 + n] = s;
      }
    }
}

// ---------------------------------------------------------------------------
// Fused PV, split-N, 2 m-groups/wave. lw computed inline from pm/ps.
// grid (g, 16, 2): b fastest. Single-buffered K/V.
// ---------------------------------------------------------------------------
__global__ __launch_bounds__(256)
void pv_k(const unsigned short* __restrict__ xk, long sXk,
          const unsigned short* __restrict__ xv, long sXv,
          const float* __restrict__ pm, const float* __restrict__ ps,
          float* __restrict__ pacc, float* __restrict__ pc) {
  __shared__ unsigned short lK[64 * 128];
  __shared__ unsigned short lV[128 * 64];
  __shared__ float lwt[64];
  int tid = threadIdx.x, wave = tid >> 6, lane = tid & 63;
  int quad = lane >> 4, l15 = lane & 15;
  int rowL4 = lane >> 4, s16 = lane & 15;
  int rowL8 = lane >> 3, s8 = lane & 7;
  int m0 = blockIdx.y * 128, b = blockIdx.x, seg = blockIdx.z;
  int nbase = seg * 1024;
  const unsigned short* Kp = xk + (long)b * sXk;
  const unsigned short* Vp = xv + (long)b * sXv;
  short8 akr[2][4];
  #pragma unroll
  for (int g2 = 0; g2 < 2; ++g2) {
    const unsigned short* arow = Kp + (long)(m0 + g2 * 64 + wave * 16 + l15) * 128;
    #pragma unroll
    for (int kf = 0; kf < 4; ++kf) akr[g2][kf] = *(const short8*)(arow + kf * 32 + quad * 8);
  }
  f32x4 acc[2][8];
  #pragma unroll
  for (int g2 = 0; g2 < 2; ++g2)
    #pragma unroll
    for (int dt = 0; dt < 8; ++dt) acc[g2][dt] = (f32x4){0.f, 0.f, 0.f, 0.f};
  float runc[2] = {0.f, 0.f};

  for (int ch = 0; ch < 16; ++ch) {
    if (ch) __syncthreads();
    #pragma unroll
    for (int t = 0; t < 4; ++t) {
      int c = t * 4 + wave;
      int rowK = c * 4 + rowL4;
      int gsegK = (s16 & 8) | ((s16 ^ (rowK & 7)) & 7);
      dma16(Kp + (long)(nbase + ch * 64 + rowK) * 128 + gsegK * 8, &lK[c * 512]);
      int rowV = c * 8 + rowL8;
      int gsegV = s8 ^ (rowV & 7);
      dma16(Vp + (long)rowV * 2048 + nbase + ch * 64 + gsegV * 8, &lV[c * 512]);
    }
    if (tid < 64) {
      int n = nbase + ch * 64 + tid;
      float m0v = pm[((long)b * 2) * 2048 + n], m1v = pm[((long)b * 2 + 1) * 2048 + n];
      float s0v = ps[((long)b * 2) * 2048 + n], s1v = ps[((long)b * 2 + 1) * 2048 + n];
      float mx = fmaxf(m0v, m1v);
      lwt[tid] = mx + __logf(s0v * __expf(m0v - mx) + s1v * __expf(m1v - mx));
    }
    __syncthreads();
    unsigned pd0[2][4], pd1[2][4];
    #pragma unroll
    for (int nf = 0; nf < 4; ++nf) {
      f32x4 sa = (f32x4){0.f, 0.f, 0.f, 0.f};
      f32x4 sb = (f32x4){0.f, 0.f, 0.f, 0.f};
      #pragma unroll
      for (int kf = 0; kf < 4; ++kf) {
        int r = nf * 16 + l15, q = kf * 4 + quad;
        int sp = (q & 8) | ((q ^ (r & 7)) & 7);
        short8 kfr = *(const short8*)&lK[r * 128 + sp * 8];
        sa = __builtin_amdgcn_mfma_f32_16x16x32_bf16(kfr, akr[0][kf], sa, 0, 0, 0);
        sb = __builtin_amdgcn_mfma_f32_16x16x32_bf16(kfr, akr[1][kf], sb, 0, 0, 0);
      }
      float4 lw4 = *(const float4*)&lwt[nf * 16 + quad * 4];
      float lwv[4] = {lw4.x, lw4.y, lw4.z, lw4.w};
      unsigned short ta[4], tb[4];
      #pragma unroll
      for (int r = 0; r < 4; ++r) {
        float p0 = __expf(sa[r] - lwv[r]);
        float p1 = __expf(sb[r] - lwv[r]);
        runc[0] += p0; runc[1] += p1;
        ta[r] = f2bf(p0); tb[r] = f2bf(p1);
      }
      pd0[0][nf] = (unsigned)ta[0] | ((unsigned)ta[1] << 16);
      pd1[0][nf] = (unsigned)ta[2] | ((unsigned)ta[3] << 16);
      pd0[1][nf] = (unsigned)tb[0] | ((unsigned)tb[1] << 16);
      pd1[1][nf] = (unsigned)tb[2] | ((unsigned)tb[3] << 16);
    }
    #pragma unroll
    for (int kc = 0; kc < 2; ++kc) {
      short8 paf[2];
      #pragma unroll
      for (int g2 = 0; g2 < 2; ++g2) {
        unsigned d0 = (quad >= 2) ? pd0[g2][2 * kc + 1] : pd0[g2][2 * kc];
        unsigned d1 = (quad >= 2) ? pd1[g2][2 * kc + 1] : pd1[g2][2 * kc];
        int s0 = ((quad & 1) << 5) + l15;
        union { unsigned u[4]; short8 v; } pu;
        pu.u[0] = (unsigned)__shfl((int)d0, s0);
        pu.u[1] = (unsigned)__shfl((int)d1, s0);
        pu.u[2] = (unsigned)__shfl((int)d0, s0 + 16);
        pu.u[3] = (unsigned)__shfl((int)d1, s0 + 16);
        paf[g2] = pu.v;
      }
      #pragma unroll
      for (int dt = 0; dt < 8; ++dt) {
        int r = dt * 16 + l15;
        int spv = (kc * 4 + quad) ^ (r & 7);
        short8 vb = *(const short8*)&lV[r * 64 + spv * 8];
        acc[0][dt] = __builtin_amdgcn_mfma_f32_16x16x32_bf16(paf[0], vb, acc[0][dt], 0, 0, 0);
        acc[1][dt] = __builtin_amdgcn_mfma_f32_16x16x32_bf16(paf[1], vb, acc[1][dt], 0, 0, 0);
      }
    }
  }
  #pragma unroll
  for (int g2 = 0; g2 < 2; ++g2) {
    float s = runc[g2];
    s += __shfl_xor(s, 16);
    s += __shfl_xor(s, 32);
    if (quad == 0)
      pc[((long)b * 2 + seg) * 2048 + m0 + g2 * 64 + wave * 16 + l15] = s;
  }
  float* pa = pacc + ((long)b * 2 + seg) * 262144;
  #pragma unroll
  for (int g2 = 0; g2 < 2; ++g2)
    #pragma unroll
    for (int dt = 0; dt < 8; ++dt) {
      int d = dt * 16 + l15;
      #pragma unroll
      for (int r = 0; r < 4; ++r)
        pa[(long)(m0 + g2 * 64 + wave * 16 + quad * 4 + r) * 128 + d] = acc[g2][dt][r];
    }
}

// combine PV partials: xrb = bf16(li - (P0+P1)/(1e-9+c0+c1)). grid (256, g).
__global__ __launch_bounds__(256)
void pvred_k(const float* __restrict__ pacc, const float* __restrict__ pc,
             const unsigned short* __restrict__ lib, long sLi, int ldLi,
             unsigned short* __restrict__ xrb, long sXr) {
  int i = blockIdx.x * 256 + threadIdx.x;
  int b = blockIdx.y;
  int m = i >> 5, d4 = (i & 31) * 4;
  float4 a0 = *(const float4*)&pacc[((long)b * 2 + 0) * 262144 + (long)m * 128 + d4];
  float4 a1 = *(const float4*)&pacc[((long)b * 2 + 1) * 262144 + (long)m * 128 + d4];
  float c = pc[((long)b * 2) * 2048 + m] + pc[((long)b * 2 + 1) * 2048 + m];
  float inv = 1.f / (1e-9f + c);
  uint2 lv = *(const uint2*)&lib[(long)b * sLi + (long)m * ldLi + d4];
  unsigned short lr[4];
  *(uint2*)lr = lv;
  unsigned short o[4];
  o[0] = f2bf(bf2f(lr[0]) - (a0.x + a1.x) * inv);
  o[1] = f2bf(bf2f(lr[1]) - (a0.y + a1.y) * inv);
  o[2] = f2bf(bf2f(lr[2]) - (a0.z + a1.z) * inv);
  o[3] = f2bf(bf2f(lr[3]) - (a0.w + a1.w) * inv);
  *(uint2*)&xrb[(long)b * sXr + (long)m * 128 + d4] = *(uint2*)&o[0];
}

// ---------------------------------------------------------------------------
__global__ void poolred_k(const float* __restrict__ pmax, const float* __restrict__ psum,
                          float* __restrict__ xmax, float* __restrict__ xavg) {
  int f = blockIdx.x * 256 + threadIdx.x, b = blockIdx.y;
  float mx = -1e30f, s = 0.f;
  #pragma unroll
  for (int t = 0; t < 16; ++t) {
    mx = fmaxf(mx, pmax[((long)b * 16 + t) * 1024 + f]);
    s += psum[((long)b * 16 + t) * 1024 + f];
  }
  xmax[(long)b * 1024 + f] = mx;
  xavg[(long)b * 1024 + f] = s * (1.f / 2048.f);
}

// pt[b][o] = sc1[o] * ( ws1[o][1024:2048].xmax + ws1[o][2048:3072].xavg )
__global__ __launch_bounds__(256)
void poolterm_k(const float* __restrict__ ws1, const float* __restrict__ xmax,
                const float* __restrict__ xavg,
                const float* __restrict__ bg, const float* __restrict__ bv,
                float* __restrict__ pt) {
  int o = blockIdx.x, b = blockIdx.y, tid = threadIdx.x;
  const float* w = ws1 + (long)o * 3072;
  float s = 0.f;
  #pragma unroll
  for (int it = 0; it < 4; ++it) {
    int c = tid + it * 256;
    s += w[1024 + c] * xmax[(long)b * 1024 + c] + w[2048 + c] * xavg[(long)b * 1024 + c];
  }
  #pragma unroll
  for (int off = 32; off; off >>= 1) s += __shfl_xor(s, off);
  __shared__ float rsm[4];
  if ((tid & 63) == 0) rsm[tid >> 6] = s;
  __syncthreads();
  if (tid == 0) {
    float sc = bg[o] * rsqrtf(bv[o] + BN_EPS);
    pt[(long)b * H1_ + o] = sc * (rsm[0] + rsm[1] + rsm[2] + rsm[3]);
  }
}

// ---------------------------------------------------------------------------
extern "C" void kernel_launch(void* const* d_in, const int* in_sizes, int n_in,
                              void* d_out, int out_size, void* d_ws, size_t ws_size,
                              hipStream_t stream) {
  const float* x      = (const float*)d_in[0];
  const float* w1     = (const float*)d_in[1];
  const float* w2     = (const float*)d_in[2];
  const float* bn1_g  = (const float*)d_in[3];
  const float* bn1_b  = (const float*)d_in[4];
  const float* bn1_m  = (const float*)d_in[5];
  const float* bn1_v  = (const float*)d_in[6];
  const float* bn2_g  = (const float*)d_in[7];
  const float* bn2_b  = (const float*)d_in[8];
  const float* bn2_m  = (const float*)d_in[9];
  const float* bn2_v  = (const float*)d_in[10];
  const float* sa_wqk = (const float*)d_in[11];
  const float* sa_wv  = (const float*)d_in[12];
  const float* sa_bv  = (const float*)d_in[13];
  const float* sa_wt  = (const float*)d_in[14];
  const float* sa_bt  = (const float*)d_in[15];
  const float* sa_g   = (const float*)d_in[16];
  const float* sa_b   = (const float*)d_in[17];
  const float* sa_m   = (const float*)d_in[18];
  const float* sa_v   = (const float*)d_in[19];
  const float* wf     = (const float*)d_in[20];
  const float* bnf_g  = (const float*)d_in[21];
  const float* bnf_b  = (const float*)d_in[22];
  const float* bnf_m  = (const float*)d_in[23];
  const float* bnf_v  = (const float*)d_in[24];
  const float* ws1    = (const float*)d_in[25];
  const float* bs1    = (const float*)d_in[26];
  const float* bns1_g = (const float*)d_in[27];
  const float* bns1_b = (const float*)d_in[28];
  const float* bns1_m = (const float*)d_in[29];
  const float* bns1_v = (const float*)d_in[30];
  const float* ws2    = (const float*)d_in[31];
  const float* bs2    = (const float*)d_in[32];
  const float* bns2_g = (const float*)d_in[33];
  const float* bns2_b = (const float*)d_in[34];
  const float* bns2_m = (const float*)d_in[35];
  const float* bns2_v = (const float*)d_in[36];
  float* out = (float*)d_out;

  float* ws = (float*)d_ws;
  size_t off = 0;
  auto alloc  = [&](size_t n) { float* p = ws + off; off += (n + 63) & ~(size_t)63; return p; };
  auto allocH = [&](size_t n) { return (unsigned short*)alloc((n + 1) / 2); };

  unsigned short* w2b  = allocH(128 * 128);
  unsigned short* wqkb = allocH(4 * 128 * 128);
  unsigned short* wvb  = allocH(4 * 128 * 128);
  unsigned short* wtb  = allocH(4 * 128 * 128);
  unsigned short* wfb  = allocH((size_t)F_ * 512);
  unsigned short* ws1b = allocH((size_t)H1_ * 1024);
  unsigned short* ws2b = allocH((size_t)128 * 512);
  float* bias_w2 = alloc(128);
  float* bias_v  = alloc(512);
  float* bias_t  = alloc(512);
  float* bias_f  = alloc(1024);
  float* bias_s1 = alloc(512);
  float* bias_s2 = alloc(128);
  float* pmax = alloc((size_t)16 * 16 * 1024);
  float* psum = alloc((size_t)16 * 16 * 1024);
  float* xmaxB = alloc((size_t)16 * 1024);
  float* xavgB = alloc((size_t)16 * 1024);
  float* ptB   = alloc((size_t)16 * 512);
  size_t fixedOff = off;

  const size_t perB = 131072 + 524288 + 1048576 + 131072 + 131072 + 131072 +
                      524288 + 12288;
  size_t wsFloats = ws_size / 4;
  int Gb = 1;
  for (int c : {16, 8, 4, 2, 1}) {
    if (fixedOff + (size_t)c * perB + 4096 <= wsFloats) { Gb = c; break; }
  }

  unsigned short* h1b    = allocH((size_t)Gb * 262144);
  unsigned short* featsb = allocH((size_t)Gb * 1048576);   // hs1b aliases
  unsigned short* fusedb = allocH((size_t)Gb * 2097152);
  unsigned short* xkb    = allocH((size_t)Gb * 262144);
  unsigned short* xvb    = allocH((size_t)Gb * 262144);
  unsigned short* xrb    = allocH((size_t)Gb * 262144);    // h0b aliases
  float* paccB = alloc((size_t)Gb * 2 * 262144);
  float* pmB   = alloc((size_t)Gb * 2 * 2048);
  float* psB   = alloc((size_t)Gb * 2 * 2048);
  float* pcB   = alloc((size_t)Gb * 2 * 2048);
  unsigned short* h0b  = xrb;
  unsigned short* hs1b = featsb;

  foldw_k<<<64, 256, 0, stream>>>(w2, 128, nullptr, bn2_g, bn2_b, bn2_m, bn2_v,
                                  w2b, bias_w2, 128, 128, 128);
  for (int i = 0; i < 4; ++i) {
    foldw_k<<<64, 256, 0, stream>>>(sa_wqk + (size_t)i * 16384, 128, nullptr,
                                    nullptr, nullptr, nullptr, nullptr,
                                    wqkb + (size_t)i * 16384, nullptr, 128, 128, 128);
    foldw_k<<<64, 256, 0, stream>>>(sa_wv + (size_t)i * 16384, 128, sa_bv + i * 128,
                                    nullptr, nullptr, nullptr, nullptr,
                                    wvb + (size_t)i * 16384, bias_v + i * 128, 128, 128, 128);
    foldw_k<<<64, 256, 0, stream>>>(sa_wt + (size_t)i * 16384, 128, sa_bt + i * 128,
                                    sa_g + i * 128, sa_b + i * 128, sa_m + i * 128, sa_v + i * 128,
                                    wtb + (size_t)i * 16384, bias_t + i * 128, 128, 128, 128);
  }
  foldw_k<<<2048, 256, 0, stream>>>(wf, 512, nullptr, bnf_g, bnf_b, bnf_m, bnf_v,
                                    wfb, bias_f, 1024, 1024, 512);
  foldw_k<<<2048, 256, 0, stream>>>(ws1, 3072, bs1, bns1_g, bns1_b, bns1_m, bns1_v,
                                    ws1b, bias_s1, 512, 512, 1024);
  foldw_k<<<256, 256, 0, stream>>>(ws2, 512, bs2, bns2_g, bns2_b, bns2_m, bns2_v,
                                   ws2b, bias_s2, 50, 128, 512);

  const long sAct = 262144, sFeat = 1048576, sFus = 2097152;
  for (int b0 = 0; b0 < B_; b0 += Gb) {
    int g = Gb;
    conv1_k<<<dim3(N_, g), 128, 0, stream>>>(x + (long)b0 * 3 * N_, w1,
                                             bn1_g, bn1_b, bn1_m, bn1_v, h0b);
    // conv2+bn2+relu -> h1b bf16 (TM=32, grid 1024)
    gemm_tok<32><<<dim3(64, 1, g), 256, 0, stream>>>(
        w2b, 128, h0b, sAct, 128, bias_w2, nullptr, 0, nullptr, 0, 0,
        h1b, sAct, 128, nullptr, nullptr, 128, 1, 0);

    for (int i = 0; i < 4; ++i) {
      const unsigned short* lib = (i == 0) ? h1b : featsb + (size_t)(i - 1) * 128;
      int ldLi = (i == 0) ? 128 : 512;
      long sLi = (i == 0) ? sAct : sFeat;
      // xk + xv in one dispatch
      gemm_kv<<<dim3(32, 2, g), 256, 0, stream>>>(
          wqkb + (size_t)i * 16384, wvb + (size_t)i * 16384, bias_v + i * 128,
          lib, sLi, ldLi, xkb, sAct, xvb, sAct);
      gram_lw<<<dim3(g, 16, 2), 256, 0, stream>>>(xkb, sAct, pmB, psB);
      pv_k<<<dim3(g, 16, 2), 256, 0, stream>>>(xkb, sAct, xvb, sAct, pmB, psB, paccB, pcB);
      pvred_k<<<dim3(256, g), 256, 0, stream>>>(paccB, pcB, lib, sLi, ldLi, xrb, sAct);
      // feats_i = li + relu(wt' @ (li - xr) + bt')   (TM=32)
      gemm_tok<32><<<dim3(64, 1, g), 256, 0, stream>>>(
          wtb + (size_t)i * 16384, 128, xrb, sAct, 128, bias_t + i * 128, nullptr, 0,
          lib, sLi, ldLi,
          featsb + (size_t)i * 128, sFeat, 512, nullptr, nullptr, 128, 1, 16);
    }

    // fused = leaky(wf' @ feats + bf') -> bf16 + pool partials
    gemm_tok<128><<<dim3(16, 8, g), 256, 0, stream>>>(
        wfb, 512, featsb, sFeat, 512, bias_f, nullptr, 0, nullptr, 0, 0,
        fusedb, sFus, 1024, pmax, psum, 512, 2, 32);
    poolred_k<<<dim3(4, g), 256, 0, stream>>>(pmax, psum, xmaxB, xavgB);
    poolterm_k<<<dim3(512, g), 256, 0, stream>>>(ws1, xmaxB, xavgB, bns1_g, bns1_v, ptB);
    // hs1 = relu(ws1' @ fused + bs1' + pt) -> bf16
    gemm_tok<128><<<dim3(16, 4, g), 256, 0, stream>>>(
        ws1b, 1024, fusedb, sFus, 1024, bias_s1, ptB, 512, nullptr, 0, 0,
        hs1b, sFeat, 512, nullptr, nullptr, 1024, 1, 0);
    // out = relu(ws2' @ hs1 + bs2') -> fp32 channel-major (TM=32)
    gemm_chan<32><<<dim3(64, 1, g), 256, 0, stream>>>(
        ws2b, 512, hs1b, sFeat, 512, bias_s2,
        out + (long)b0 * OUT_ * N_, (long)OUT_ * N_, 2048, nullptr, 0, 0,
        512, 50, 1);
  }
}